// Round 1
// baseline (11645.683 us; speedup 1.0000x reference)
//
#include <hip/hip_runtime.h>

// ---------------------------------------------------------------------------
// GPT encoder-decoder forward on MI355X (gfx950).
// Round 0: correctness-first full pipeline, all GEMMs on bf16 MFMA.
// ---------------------------------------------------------------------------

typedef __bf16 bf16x8 __attribute__((ext_vector_type(8)));
typedef float  f32x4  __attribute__((ext_vector_type(4)));

constexpr int Lc = 6, Dc = 768, Hc = 12, HDc = 64, Vc = 32000;
constexpr int Bc = 4, Tc = 1024, FFc = 3072;
constexpr int Mtot = Bc * Tc;  // 4096

static __device__ __forceinline__ unsigned short f2bf(float f) {
  union { float f; unsigned u; } x; x.f = f;
  unsigned r = x.u + 0x7fffu + ((x.u >> 16) & 1u);   // RNE
  return (unsigned short)(r >> 16);
}

// ---------------------------------------------------------------------------
// Block reductions (256 threads = 4 waves)
// ---------------------------------------------------------------------------
static __device__ __forceinline__ float blockReduceSum(float v, float* red) {
  #pragma unroll
  for (int o = 32; o; o >>= 1) v += __shfl_xor(v, o, 64);
  int w = threadIdx.x >> 6;
  __syncthreads();
  if ((threadIdx.x & 63) == 0) red[w] = v;
  __syncthreads();
  return red[0] + red[1] + red[2] + red[3];
}
static __device__ __forceinline__ float blockReduceMax(float v, float* red) {
  #pragma unroll
  for (int o = 32; o; o >>= 1) v = fmaxf(v, __shfl_xor(v, o, 64));
  int w = threadIdx.x >> 6;
  __syncthreads();
  if ((threadIdx.x & 63) == 0) red[w] = v;
  __syncthreads();
  return fmaxf(fmaxf(red[0], red[1]), fmaxf(red[2], red[3]));
}

// ---------------------------------------------------------------------------
// Embedding: out[r,:] = tok[idx[r],:] + pos[r % T,:]
// ---------------------------------------------------------------------------
__global__ __launch_bounds__(256) void embed_k(const int* __restrict__ idx,
                                               const float* __restrict__ tok,
                                               const float* __restrict__ pos,
                                               float* __restrict__ out) {
  const long row = blockIdx.x;
  const int t = (int)(row % Tc);
  const long id = idx[row];
  #pragma unroll
  for (int j = 0; j < 3; j++) {
    int e = threadIdx.x + j * 256;
    out[row * Dc + e] = tok[id * Dc + e] + pos[(long)t * Dc + e];
  }
}

// ---------------------------------------------------------------------------
// LayerNorm over D=768, output bf16 (feeds GEMMs only)
// ---------------------------------------------------------------------------
__global__ __launch_bounds__(256) void ln_k(const float* __restrict__ X,
                                            const float* __restrict__ g,
                                            const float* __restrict__ bta,
                                            unsigned short* __restrict__ out) {
  __shared__ float red[4];
  const long row = blockIdx.x;
  const int tid = threadIdx.x;
  float v[3];
  #pragma unroll
  for (int j = 0; j < 3; j++) v[j] = X[row * Dc + tid + j * 256];
  float s = v[0] + v[1] + v[2];
  s = blockReduceSum(s, red);
  float mean = s * (1.f / 768.f);
  float q = 0.f;
  #pragma unroll
  for (int j = 0; j < 3; j++) { float d = v[j] - mean; q += d * d; }
  q = blockReduceSum(q, red);
  float rstd = rsqrtf(q * (1.f / 768.f) + 1e-5f);
  #pragma unroll
  for (int j = 0; j < 3; j++) {
    int e = tid + j * 256;
    out[row * Dc + e] = f2bf((v[j] - mean) * rstd * g[e] + bta[e]);
  }
}

// ---------------------------------------------------------------------------
// Row softmax over T=1024 scores (f32), writes bf16 P in-place into the same
// rows (row byte-stride stays 4096B; bf16 row occupies the first 2048B).
// ---------------------------------------------------------------------------
template <bool CAUSAL>
__global__ __launch_bounds__(256) void softmax_k(float* __restrict__ S) {
  __shared__ float red[4];
  const long row = blockIdx.x;
  const int qpos = (int)(row % Tc);
  float* srow = S + row * (long)Tc;
  const int tid = threadIdx.x;
  float v[4]; bool ok[4];
  #pragma unroll
  for (int j = 0; j < 4; j++) {
    int e = tid + j * 256;
    v[j] = srow[e];
    ok[j] = CAUSAL ? (e <= qpos) : true;
  }
  float mx = -1e30f;
  #pragma unroll
  for (int j = 0; j < 4; j++) if (ok[j]) mx = fmaxf(mx, v[j]);
  mx = blockReduceMax(mx, red);
  float p[4]; float sum = 0.f;
  #pragma unroll
  for (int j = 0; j < 4; j++) { p[j] = ok[j] ? __expf(v[j] - mx) : 0.f; sum += p[j]; }
  sum = blockReduceSum(sum, red);
  float inv = 1.f / sum;
  unsigned short* prow = reinterpret_cast<unsigned short*>(srow);
  #pragma unroll
  for (int j = 0; j < 4; j++) prow[tid + j * 256] = f2bf(p[j] * inv);
}

// ---------------------------------------------------------------------------
// Tiled MFMA GEMM.  C[M,N] = A[M,K] * B  (+bias)(+relu)(+residual)
//   A: bf16 row-major (lda), per-batch offsets offA = sAb*b + sAh*h
//   B: BTRANS ? bf16 [N][K] row-major ("B^T", e.g. K-rows for QK^T)
//            : row-major [K][N], f32 (weights, converted on the fly) or bf16
//   C: f32 or bf16.  Batch z = blockIdx.z; b=z/nH, h=z%nH.
// 4 waves in 2x2; wave computes (MF*16) x (NF*16).  BK=32 -> 1 mfma/frag.
// ---------------------------------------------------------------------------
template <int BM, int BN, int BK, int MF, int NF,
          bool BTRANS, bool BF32, bool HASBIAS, bool RELU, bool HASRES, bool OUTBF>
__global__ __launch_bounds__(256) void gemm_k(
    const unsigned short* __restrict__ A, long sAb, long sAh, int lda,
    const void* __restrict__ Bp, long sBb, long sBh, int ldb,
    void* Cp, long sCb, long sCh, int ldc,
    const float* __restrict__ bias,
    const float* Res, long sRb, long sRh, int ldr,
    int K, int nH, float alpha) {
  constexpr int LDSS = BK + 8;  // pad: 40 bf16 = 80B rows, keeps 16B align, 2-way banks (free)
  __shared__ unsigned short Asm[BM * LDSS];
  __shared__ unsigned short Bsm[BN * LDSS];

  const int tid = threadIdx.x;
  const int lane = tid & 63;
  const int wave = tid >> 6;
  const int wr = wave >> 1, wc = wave & 1;
  const int lane16 = lane & 15;
  const int koff = (lane >> 4) * 8;

  const int z = blockIdx.z;
  const int bb = z / nH, hh = z % nH;
  const long offA = sAb * bb + sAh * hh;
  const long offB = sBb * bb + sBh * hh;
  const long offC = sCb * bb + sCh * hh;
  const long offR = HASRES ? (sRb * bb + sRh * hh) : 0;

  const int rowM0 = blockIdx.y * BM;
  const int n0 = blockIdx.x * BN;

  f32x4 acc[MF][NF];
  #pragma unroll
  for (int m = 0; m < MF; m++)
    #pragma unroll
    for (int n = 0; n < NF; n++)
      #pragma unroll
      for (int r = 0; r < 4; r++) acc[m][n][r] = 0.f;

  for (int k0 = 0; k0 < K; k0 += BK) {
    __syncthreads();
    // ---- stage A tile [BM][BK] (bf16, vectorized 16B) ----
    for (int i = tid; i < BM * BK / 8; i += 256) {
      int row = i / (BK / 8), c8 = i % (BK / 8);
      bf16x8 v = *reinterpret_cast<const bf16x8*>(A + offA + (long)(rowM0 + row) * lda + k0 + c8 * 8);
      *reinterpret_cast<bf16x8*>(&Asm[row * LDSS + c8 * 8]) = v;
    }
    // ---- stage B tile into Bsm[N][K] layout ----
    if constexpr (BTRANS) {
      const unsigned short* Bb_ = (const unsigned short*)Bp;
      for (int i = tid; i < BN * BK / 8; i += 256) {
        int row = i / (BK / 8), c8 = i % (BK / 8);
        bf16x8 v = *reinterpret_cast<const bf16x8*>(Bb_ + offB + (long)(n0 + row) * ldb + k0 + c8 * 8);
        *reinterpret_cast<bf16x8*>(&Bsm[row * LDSS + c8 * 8]) = v;
      }
    } else if constexpr (BF32) {
      const float* Bf = (const float*)Bp;
      for (int i = tid; i < BK * BN / 4; i += 256) {
        int kk = i / (BN / 4), c4 = i % (BN / 4);
        f32x4 v = *reinterpret_cast<const f32x4*>(Bf + offB + (long)(k0 + kk) * ldb + n0 + c4 * 4);
        #pragma unroll
        for (int j = 0; j < 4; j++) Bsm[(c4 * 4 + j) * LDSS + kk] = f2bf(v[j]);
      }
    } else {
      const unsigned short* Bb_ = (const unsigned short*)Bp;
      for (int i = tid; i < BK * BN / 8; i += 256) {
        int kk = i / (BN / 8), c8 = i % (BN / 8);
        bf16x8 v = *reinterpret_cast<const bf16x8*>(Bb_ + offB + (long)(k0 + kk) * ldb + n0 + c8 * 8);
        const unsigned short* vs = (const unsigned short*)&v;
        #pragma unroll
        for (int j = 0; j < 8; j++) Bsm[(c8 * 8 + j) * LDSS + kk] = vs[j];
      }
    }
    __syncthreads();

    // ---- fragments + MFMA ----
    bf16x8 af[MF], bfr[NF];
    #pragma unroll
    for (int m = 0; m < MF; m++)
      af[m] = *reinterpret_cast<const bf16x8*>(&Asm[(wr * MF * 16 + m * 16 + lane16) * LDSS + koff]);
    #pragma unroll
    for (int n = 0; n < NF; n++)
      bfr[n] = *reinterpret_cast<const bf16x8*>(&Bsm[(wc * NF * 16 + n * 16 + lane16) * LDSS + koff]);
    #pragma unroll
    for (int m = 0; m < MF; m++)
      #pragma unroll
      for (int n = 0; n < NF; n++)
        acc[m][n] = __builtin_amdgcn_mfma_f32_16x16x32_bf16(af[m], bfr[n], acc[m][n], 0, 0, 0);
  }

  // ---- epilogue: C/D layout col=lane&15, row=(lane>>4)*4+reg (verified) ----
  const int r0 = rowM0 + wr * MF * 16;
  const int c0 = n0 + wc * NF * 16;
  #pragma unroll
  for (int m = 0; m < MF; m++) {
    #pragma unroll
    for (int n = 0; n < NF; n++) {
      #pragma unroll
      for (int r = 0; r < 4; r++) {
        int rr = r0 + m * 16 + (lane >> 4) * 4 + r;
        int cc = c0 + n * 16 + lane16;
        float v = acc[m][n][r] * alpha;
        if constexpr (HASBIAS) v += bias[cc];
        if constexpr (RELU) v = fmaxf(v, 0.f);
        if constexpr (HASRES) v += Res[offR + (long)rr * ldr + cc];
        if constexpr (OUTBF) ((unsigned short*)Cp)[offC + (long)rr * ldc + cc] = f2bf(v);
        else                 ((float*)Cp)[offC + (long)rr * ldc + cc] = v;
      }
    }
  }
}

// ---------------------------------------------------------------------------
extern "C" void kernel_launch(void* const* d_in, const int* in_sizes, int n_in,
                              void* d_out, int out_size, void* d_ws, size_t ws_size,
                              hipStream_t stream) {
  (void)in_sizes; (void)n_in; (void)out_size;

  const int*   idx      = (const int*)d_in[0];
  const int*   enc_in   = (const int*)d_in[1];
  const float* enc_tok  = (const float*)d_in[2];
  const float* enc_pos  = (const float*)d_in[3];
  const float* enc_qkv  = (const float*)d_in[4];
  const float* enc_wo   = (const float*)d_in[5];
  const float* enc_bo   = (const float*)d_in[6];
  const float* enc_w1   = (const float*)d_in[7];
  const float* enc_b1   = (const float*)d_in[8];
  const float* enc_w2   = (const float*)d_in[9];
  const float* enc_b2   = (const float*)d_in[10];
  const float* enc_ln1g = (const float*)d_in[11];
  const float* enc_ln1b = (const float*)d_in[12];
  const float* enc_ln2g = (const float*)d_in[13];
  const float* enc_ln2b = (const float*)d_in[14];
  const float* enc_lnfg = (const float*)d_in[15];
  const float* enc_lnfb = (const float*)d_in[16];
  const float* dec_tok  = (const float*)d_in[17];
  const float* dec_pos  = (const float*)d_in[18];
  const float* dec_qkv  = (const float*)d_in[19];
  const float* dec_wo   = (const float*)d_in[20];
  const float* dec_bo   = (const float*)d_in[21];
  const float* dec_cqkv = (const float*)d_in[22];
  const float* dec_cwo  = (const float*)d_in[23];
  const float* dec_cbo  = (const float*)d_in[24];
  const float* dec_w1   = (const float*)d_in[25];
  const float* dec_b1   = (const float*)d_in[26];
  const float* dec_w2   = (const float*)d_in[27];
  const float* dec_b2   = (const float*)d_in[28];
  const float* dec_ln1g = (const float*)d_in[29];
  const float* dec_ln1b = (const float*)d_in[30];
  const float* dec_ln2g = (const float*)d_in[31];
  const float* dec_ln2b = (const float*)d_in[32];
  const float* dec_ln3g = (const float*)d_in[33];
  const float* dec_ln3b = (const float*)d_in[34];
  const float* dec_lnfg = (const float*)d_in[35];
  const float* dec_lnfb = (const float*)d_in[36];
  const float* lm_w     = (const float*)d_in[37];
  const float* lm_b     = (const float*)d_in[38];

  // ---- workspace layout (~276 MiB) ----
  char* ws = (char*)d_ws;
  const size_t need = (size_t)Bc * Hc * Tc * Tc * 4 + 2ull * Mtot * Dc * 4 +
                      6ull * Mtot * Dc * 2 + (size_t)Mtot * FFc * 2;
  if (ws_size < need) return;  // fail loudly (output stays poisoned)

  float* scores = (float*)ws;            ws += (size_t)Bc * Hc * Tc * Tc * 4;
  float* xe     = (float*)ws;            ws += (size_t)Mtot * Dc * 4;
  float* xd     = (float*)ws;            ws += (size_t)Mtot * Dc * 4;
  unsigned short* hbf  = (unsigned short*)ws; ws += (size_t)Mtot * Dc * 2;
  unsigned short* qkvb = (unsigned short*)ws; ws += 3ull * Mtot * Dc * 2;
  unsigned short* ao   = (unsigned short*)ws; ws += (size_t)Mtot * Dc * 2;
  unsigned short* mid  = (unsigned short*)ws; ws += (size_t)Mtot * FFc * 2;
  unsigned short* eo   = (unsigned short*)ws;
  unsigned short* qb = qkvb;
  unsigned short* kb = qkvb + (size_t)Mtot * Dc;
  unsigned short* vb = qkvb + 2ull * Mtot * Dc;

  const dim3 TB(256);

  auto LN = [&](const float* X, const float* g, const float* b, unsigned short* o) {
    ln_k<<<dim3(Mtot), TB, 0, stream>>>(X, g, b, o);
  };
  // x @ W3[z] -> qkv (z-batched over 3 weight matrices)
  auto QKV3 = [&](const unsigned short* Abf, const float* W3) {
    gemm_k<128,128,32,4,4,false,true,false,false,false,true>
      <<<dim3(Dc/128, Mtot/128, 3), TB, 0, stream>>>(
        Abf, 0, 0, Dc, W3, (long)Dc*Dc, 0, Dc,
        qkvb, (long)Mtot*Dc, 0, Dc, nullptr, nullptr, 0, 0, 0, Dc, 1, 1.f);
  };
  auto PROJ1 = [&](const unsigned short* Abf, const float* W, unsigned short* Cb) {
    gemm_k<128,128,32,4,4,false,true,false,false,false,true>
      <<<dim3(Dc/128, Mtot/128, 1), TB, 0, stream>>>(
        Abf, 0, 0, Dc, W, 0, 0, Dc,
        Cb, 0, 0, Dc, nullptr, nullptr, 0, 0, 0, Dc, 1, 1.f);
  };
  auto KV2 = [&](const unsigned short* Abf, const float* W2) {  // k and v from enc_out
    gemm_k<128,128,32,4,4,false,true,false,false,false,true>
      <<<dim3(Dc/128, Mtot/128, 2), TB, 0, stream>>>(
        Abf, 0, 0, Dc, W2, (long)Dc*Dc, 0, Dc,
        kb, (long)Mtot*Dc, 0, Dc, nullptr, nullptr, 0, 0, 0, Dc, 1, 1.f);
  };
  auto SCORES = [&]() {  // scores[b,h,q,k] = 0.125 * q . k
    gemm_k<128,128,32,4,4,true,false,false,false,false,false>
      <<<dim3(Tc/128, Tc/128, Bc*Hc), TB, 0, stream>>>(
        qb, (long)Tc*Dc, HDc, Dc,
        kb, (long)Tc*Dc, HDc, Dc,
        scores, (long)Hc*Tc*Tc, (long)Tc*Tc, Tc,
        nullptr, nullptr, 0, 0, 0, HDc, Hc, 0.125f);
  };
  auto SMAX = [&](bool causal) {
    if (causal) softmax_k<true ><<<dim3(Bc*Hc*Tc), TB, 0, stream>>>(scores);
    else        softmax_k<false><<<dim3(Bc*Hc*Tc), TB, 0, stream>>>(scores);
  };
  auto PV = [&]() {  // ao[b,q,h,:] = P[b,h,q,:] @ V
    gemm_k<128,64,32,4,2,false,false,false,false,false,true>
      <<<dim3(1, Tc/128, Bc*Hc), TB, 0, stream>>>(
        (const unsigned short*)scores, (long)Hc*Tc*Tc*2, (long)Tc*Tc*2, 2*Tc,
        vb, (long)Tc*Dc, HDc, Dc,
        ao, (long)Tc*Dc, HDc, Dc,
        nullptr, nullptr, 0, 0, 0, Tc, Hc, 1.f);
  };
  auto ORES = [&](const unsigned short* Abf, const float* W, const float* bias, float* X) {
    gemm_k<128,128,32,4,4,false,true,true,false,true,false>
      <<<dim3(Dc/128, Mtot/128, 1), TB, 0, stream>>>(
        Abf, 0, 0, Dc, W, 0, 0, Dc,
        X, 0, 0, Dc, bias, X, 0, 0, Dc, Dc, 1, 1.f);
  };
  auto FFN1 = [&](const unsigned short* Abf, const float* W, const float* bias) {
    gemm_k<128,128,32,4,4,false,true,true,true,false,true>
      <<<dim3(FFc/128, Mtot/128, 1), TB, 0, stream>>>(
        Abf, 0, 0, Dc, W, 0, 0, FFc,
        mid, 0, 0, FFc, bias, nullptr, 0, 0, 0, Dc, 1, 1.f);
  };
  auto FFN2 = [&](const float* W, const float* bias, float* X) {
    gemm_k<128,128,32,4,4,false,true,true,false,true,false>
      <<<dim3(Dc/128, Mtot/128, 1), TB, 0, stream>>>(
        mid, 0, 0, FFc, W, 0, 0, Dc,
        X, 0, 0, Dc, bias, X, 0, 0, Dc, FFc, 1, 1.f);
  };

  // ======================= encoder =======================
  embed_k<<<dim3(Mtot), TB, 0, stream>>>(enc_in, enc_tok, enc_pos, xe);
  for (int i = 0; i < Lc; i++) {
    const float* Wqkv = enc_qkv + (size_t)i * 3 * Dc * Dc;
    LN(xe, enc_ln1g + i * Dc, enc_ln1b + i * Dc, hbf);
    QKV3(hbf, Wqkv);
    SCORES(); SMAX(true); PV();
    ORES(ao, enc_wo + (size_t)i * Dc * Dc, enc_bo + i * Dc, xe);
    LN(xe, enc_ln2g + i * Dc, enc_ln2b + i * Dc, hbf);
    FFN1(hbf, enc_w1 + (size_t)i * Dc * FFc, enc_b1 + i * FFc);
    FFN2(enc_w2 + (size_t)i * FFc * Dc, enc_b2 + i * Dc, xe);
  }
  LN(xe, enc_lnfg, enc_lnfb, eo);

  // ======================= decoder =======================
  embed_k<<<dim3(Mtot), TB, 0, stream>>>(idx, dec_tok, dec_pos, xd);
  for (int i = 0; i < Lc; i++) {
    // self-attention (causal)
    LN(xd, dec_ln1g + i * Dc, dec_ln1b + i * Dc, hbf);
    QKV3(hbf, dec_qkv + (size_t)i * 3 * Dc * Dc);
    SCORES(); SMAX(true); PV();
    ORES(ao, dec_wo + (size_t)i * Dc * Dc, dec_bo + i * Dc, xd);
    // cross-attention (non-causal; K/V from encoder output)
    LN(xd, dec_ln2g + i * Dc, dec_ln2b + i * Dc, hbf);
    const float* Wc = dec_cqkv + (size_t)i * 3 * Dc * Dc;
    PROJ1(hbf, Wc, qb);
    KV2(eo, Wc + (size_t)Dc * Dc);
    SCORES(); SMAX(false); PV();
    ORES(ao, dec_cwo + (size_t)i * Dc * Dc, dec_cbo + i * Dc, xd);
    // FFN
    LN(xd, dec_ln3g + i * Dc, dec_ln3b + i * Dc, hbf);
    FFN1(hbf, dec_w1 + (size_t)i * Dc * FFc, dec_b1 + i * FFc);
    FFN2(dec_w2 + (size_t)i * FFc * Dc, dec_b2 + i * Dc, xd);
  }
  LN(xd, dec_lnfg, dec_lnfb, hbf);

  // ======================= LM head =======================
  gemm_k<128,128,32,4,4,false,true,true,false,false,false>
    <<<dim3(Vc/128, Mtot/128, 1), TB, 0, stream>>>(
      hbf, 0, 0, Dc, lm_w, 0, 0, Vc,
      (float*)d_out, 0, 0, Vc, lm_b, nullptr, 0, 0, 0, Dc, 1, 1.f);
}

// Round 2
// 5919.944 us; speedup vs baseline: 1.9672x; 1.9672x over previous
//
#include <hip/hip_runtime.h>

// ---------------------------------------------------------------------------
// GPT encoder-decoder forward on MI355X (gfx950).
// Round 2: all-bf16 MFMA GEMMs with global_load_lds + source-swizzled LDS,
// weights pre-transposed to bf16 in the unused tail of d_out.
// ---------------------------------------------------------------------------

typedef __bf16 bf16x8 __attribute__((ext_vector_type(8)));
typedef float  f32x4  __attribute__((ext_vector_type(4)));
typedef unsigned short u16x4 __attribute__((ext_vector_type(4)));
typedef unsigned short u16x8 __attribute__((ext_vector_type(8)));

constexpr int Lc = 6, Dc = 768, Hc = 12, HDc = 64, Vc = 32000;
constexpr int Bc = 4, Tc = 1024, FFc = 3072;
constexpr int Mtot = Bc * Tc;  // 4096

static __device__ __forceinline__ unsigned short f2bf(float f) {
  union { float f; unsigned u; } x; x.f = f;
  unsigned r = x.u + 0x7fffu + ((x.u >> 16) & 1u);   // RNE
  return (unsigned short)(r >> 16);
}

static __device__ __forceinline__ void gl_lds16(const unsigned short* g, unsigned short* l) {
  __builtin_amdgcn_global_load_lds(
      (const __attribute__((address_space(1))) unsigned int*)g,
      (__attribute__((address_space(3))) unsigned int*)l, 16, 0, 0);
}

// ---------------------------------------------------------------------------
// Block reductions (256 threads = 4 waves)
// ---------------------------------------------------------------------------
static __device__ __forceinline__ float blockReduceSum(float v, float* red) {
  #pragma unroll
  for (int o = 32; o; o >>= 1) v += __shfl_xor(v, o, 64);
  int w = threadIdx.x >> 6;
  __syncthreads();
  if ((threadIdx.x & 63) == 0) red[w] = v;
  __syncthreads();
  return red[0] + red[1] + red[2] + red[3];
}
static __device__ __forceinline__ float blockReduceMax(float v, float* red) {
  #pragma unroll
  for (int o = 32; o; o >>= 1) v = fmaxf(v, __shfl_xor(v, o, 64));
  int w = threadIdx.x >> 6;
  __syncthreads();
  if ((threadIdx.x & 63) == 0) red[w] = v;
  __syncthreads();
  return fmaxf(fmaxf(red[0], red[1]), fmaxf(red[2], red[3]));
}

// ---------------------------------------------------------------------------
// Weight transpose+convert: W f32 [K][N] -> WT bf16 [N][K], batched over z.
// ---------------------------------------------------------------------------
__global__ __launch_bounds__(256) void wconv_k(const float* __restrict__ W,
                                               unsigned short* __restrict__ WT,
                                               int K, int N) {
  __shared__ float t[32][33];
  const long zoff = (long)blockIdx.z * K * N;
  const int k0 = blockIdx.x * 32, n0 = blockIdx.y * 32;
  const int tid = threadIdx.x;
  const int rr = tid >> 3;            // 0..31
  const int cc = (tid & 7) * 4;       // 0..28
  f32x4 v = *reinterpret_cast<const f32x4*>(W + zoff + (long)(k0 + rr) * N + n0 + cc);
  #pragma unroll
  for (int j = 0; j < 4; j++) t[rr][cc + j] = v[j];
  __syncthreads();
  u16x4 o;
  #pragma unroll
  for (int j = 0; j < 4; j++) o[j] = f2bf(t[cc + j][rr]);
  *reinterpret_cast<u16x4*>(WT + zoff + (long)(n0 + rr) * K + k0 + cc) = o;
}

// ---------------------------------------------------------------------------
// V transpose: vb bf16 [B*T][D] (head h cols) -> vT bf16 [B*H][HD][T]
// ---------------------------------------------------------------------------
__global__ __launch_bounds__(256) void vtrans_k(const unsigned short* __restrict__ V,
                                                unsigned short* __restrict__ VT) {
  __shared__ unsigned short t[64][65];
  const int bh = blockIdx.y;
  const int b = bh / Hc, h = bh % Hc;
  const int t0 = blockIdx.x * 64;
  const int tid = threadIdx.x;
  const int rr = tid >> 3;            // 0..31
  const int c8 = (tid & 7) * 8;
  #pragma unroll
  for (int rep = 0; rep < 2; rep++) {
    int row = rep * 32 + rr;
    u16x8 v = *reinterpret_cast<const u16x8*>(V + (long)(b * Tc + t0 + row) * Dc + h * HDc + c8);
    #pragma unroll
    for (int j = 0; j < 8; j++) t[row][c8 + j] = v[j];
  }
  __syncthreads();
  #pragma unroll
  for (int rep = 0; rep < 2; rep++) {
    int hd = rep * 32 + rr;
    u16x8 o;
    #pragma unroll
    for (int j = 0; j < 8; j++) o[j] = t[c8 + j][hd];
    *reinterpret_cast<u16x8*>(VT + ((long)bh * HDc + hd) * Tc + t0 + c8) = o;
  }
}

// ---------------------------------------------------------------------------
// Embedding
// ---------------------------------------------------------------------------
__global__ __launch_bounds__(256) void embed_k(const int* __restrict__ idx,
                                               const float* __restrict__ tok,
                                               const float* __restrict__ pos,
                                               float* __restrict__ out) {
  const long row = blockIdx.x;
  const int t = (int)(row % Tc);
  const long id = idx[row];
  #pragma unroll
  for (int j = 0; j < 3; j++) {
    int e = threadIdx.x + j * 256;
    out[row * Dc + e] = tok[id * Dc + e] + pos[(long)t * Dc + e];
  }
}

// ---------------------------------------------------------------------------
// LayerNorm over D=768, output bf16
// ---------------------------------------------------------------------------
__global__ __launch_bounds__(256) void ln_k(const float* __restrict__ X,
                                            const float* __restrict__ g,
                                            const float* __restrict__ bta,
                                            unsigned short* __restrict__ out) {
  __shared__ float red[4];
  const long row = blockIdx.x;
  const int tid = threadIdx.x;
  float v[3];
  #pragma unroll
  for (int j = 0; j < 3; j++) v[j] = X[row * Dc + tid + j * 256];
  float s = v[0] + v[1] + v[2];
  s = blockReduceSum(s, red);
  float mean = s * (1.f / 768.f);
  float q = 0.f;
  #pragma unroll
  for (int j = 0; j < 3; j++) { float d = v[j] - mean; q += d * d; }
  q = blockReduceSum(q, red);
  float rstd = rsqrtf(q * (1.f / 768.f) + 1e-5f);
  #pragma unroll
  for (int j = 0; j < 3; j++) {
    int e = tid + j * 256;
    out[row * Dc + e] = f2bf((v[j] - mean) * rstd * g[e] + bta[e]);
  }
}

// ---------------------------------------------------------------------------
// Row softmax over T=1024 f32 scores, writes bf16 P in-place
// ---------------------------------------------------------------------------
template <bool CAUSAL>
__global__ __launch_bounds__(256) void softmax_k(float* __restrict__ S) {
  __shared__ float red[4];
  const long row = blockIdx.x;
  const int qpos = (int)(row % Tc);
  float* srow = S + row * (long)Tc;
  const int tid = threadIdx.x;
  float v[4]; bool ok[4];
  #pragma unroll
  for (int j = 0; j < 4; j++) {
    int e = tid + j * 256;
    v[j] = srow[e];
    ok[j] = CAUSAL ? (e <= qpos) : true;
  }
  float mx = -1e30f;
  #pragma unroll
  for (int j = 0; j < 4; j++) if (ok[j]) mx = fmaxf(mx, v[j]);
  mx = blockReduceMax(mx, red);
  float p[4]; float sum = 0.f;
  #pragma unroll
  for (int j = 0; j < 4; j++) { p[j] = ok[j] ? __expf(v[j] - mx) : 0.f; sum += p[j]; }
  sum = blockReduceSum(sum, red);
  float inv = 1.f / sum;
  unsigned short* prow = reinterpret_cast<unsigned short*>(srow);
  #pragma unroll
  for (int j = 0; j < 4; j++) prow[tid + j * 256] = f2bf(p[j] * inv);
}

// ---------------------------------------------------------------------------
// MFMA GEMM, m97 structure. C[M,N] = alpha * A[M,K] * BT[N,K]^T (+bias)(+relu)(+res)
//   A, BT bf16; C f32 or bf16. grid.x = M/BM (fast), grid.y = N/BN, grid.z batch.
//   global_load_lds(16B) into linear LDS; XOR swizzle via permuted SOURCE slot,
//   frag ds_read_b128 at slot s ^ ((lane16>>1)&3)  -> 2-way banks (free).
// ---------------------------------------------------------------------------
template <int BM, int BN, int MF, int NF, bool HASBIAS, bool RELU, bool HASRES, bool OUTBF>
__global__ __launch_bounds__(256) void gemm_k(
    const unsigned short* __restrict__ A, long sAb, long sAh, int lda,
    const unsigned short* __restrict__ BT, long sBb, long sBh, int ldb,
    void* Cp, long sCb, long sCh, int ldc,
    const float* __restrict__ bias,
    const float* __restrict__ Res, int ldr,
    int K, int nH, float alpha) {
  constexpr int BK = 32;
  __shared__ __align__(16) unsigned short Asm[BM * BK];
  __shared__ __align__(16) unsigned short Bsm[BN * BK];

  const int tid = threadIdx.x;
  const int lane = tid & 63;
  const int w = tid >> 6;
  const int wr = w >> 1, wc = w & 1;
  const int lane16 = lane & 15;

  const int z = blockIdx.z;
  const int bb = z / nH, hh = z % nH;
  const long offA = sAb * bb + sAh * hh;
  const long offB = sBb * bb + sBh * hh;
  const long offC = sCb * bb + sCh * hh;

  const int m0 = blockIdx.x * BM;
  const int n0 = blockIdx.y * BN;

  // staging: lane i -> row base+ i/4, stores global slot (i&3)^((i>>3)&3)
  const int srow = lane >> 2;
  const int g8 = (((lane & 3) ^ ((lane >> 3) & 3)) * 8);
  // frag read: slot s=lane>>4 stored at s ^ ((lane16>>1)&3)
  const int kslot = ((lane >> 4) ^ ((lane16 >> 1) & 3)) * 8;

  const unsigned short* Ab = A + offA + (long)m0 * lda;
  const unsigned short* Bb = BT + offB + (long)n0 * ldb;

  // per-lane global row pointers (k0 added in loop)
  const unsigned short* aP[BM / 64];
  #pragma unroll
  for (int j = 0; j < BM / 64; j++)
    aP[j] = Ab + (long)(w * (BM / 4) + j * 16 + srow) * lda + g8;
  const unsigned short* bP[BN / 64];
  #pragma unroll
  for (int j = 0; j < BN / 64; j++)
    bP[j] = Bb + (long)(w * (BN / 4) + j * 16 + srow) * ldb + g8;

  f32x4 acc[MF][NF];
  #pragma unroll
  for (int m = 0; m < MF; m++)
    #pragma unroll
    for (int n = 0; n < NF; n++)
      #pragma unroll
      for (int r = 0; r < 4; r++) acc[m][n][r] = 0.f;

  for (int k0 = 0; k0 < K; k0 += BK) {
    __syncthreads();
    #pragma unroll
    for (int j = 0; j < BM / 64; j++)
      gl_lds16(aP[j] + k0, &Asm[(w * (BM / 4) + j * 16) * BK]);
    #pragma unroll
    for (int j = 0; j < BN / 64; j++)
      gl_lds16(bP[j] + k0, &Bsm[(w * (BN / 4) + j * 16) * BK]);
    __syncthreads();

    bf16x8 af[MF], bfr[NF];
    #pragma unroll
    for (int m = 0; m < MF; m++)
      af[m] = *reinterpret_cast<const bf16x8*>(&Asm[(wr * MF * 16 + m * 16 + lane16) * BK + kslot]);
    #pragma unroll
    for (int n = 0; n < NF; n++)
      bfr[n] = *reinterpret_cast<const bf16x8*>(&Bsm[(wc * NF * 16 + n * 16 + lane16) * BK + kslot]);
    #pragma unroll
    for (int m = 0; m < MF; m++)
      #pragma unroll
      for (int n = 0; n < NF; n++)
        acc[m][n] = __builtin_amdgcn_mfma_f32_16x16x32_bf16(af[m], bfr[n], acc[m][n], 0, 0, 0);
  }

  const int r0 = m0 + wr * MF * 16;
  const int c0 = n0 + wc * NF * 16;
  #pragma unroll
  for (int m = 0; m < MF; m++) {
    #pragma unroll
    for (int n = 0; n < NF; n++) {
      #pragma unroll
      for (int r = 0; r < 4; r++) {
        int rr = r0 + m * 16 + (lane >> 4) * 4 + r;
        int cc = c0 + n * 16 + lane16;
        float v = acc[m][n][r] * alpha;
        if constexpr (HASBIAS) v += bias[cc];
        if constexpr (RELU) v = fmaxf(v, 0.f);
        if constexpr (HASRES) v += Res[offC + (long)rr * ldr + cc];
        if constexpr (OUTBF) ((unsigned short*)Cp)[offC + (long)rr * ldc + cc] = f2bf(v);
        else                 ((float*)Cp)[offC + (long)rr * ldc + cc] = v;
      }
    }
  }
}

// ---------------------------------------------------------------------------
extern "C" void kernel_launch(void* const* d_in, const int* in_sizes, int n_in,
                              void* d_out, int out_size, void* d_ws, size_t ws_size,
                              hipStream_t stream) {
  (void)in_sizes; (void)n_in; (void)out_size;

  const int*   idx      = (const int*)d_in[0];
  const int*   enc_in   = (const int*)d_in[1];
  const float* enc_tok  = (const float*)d_in[2];
  const float* enc_pos  = (const float*)d_in[3];
  const float* enc_qkv  = (const float*)d_in[4];
  const float* enc_wo   = (const float*)d_in[5];
  const float* enc_bo   = (const float*)d_in[6];
  const float* enc_w1   = (const float*)d_in[7];
  const float* enc_b1   = (const float*)d_in[8];
  const float* enc_w2   = (const float*)d_in[9];
  const float* enc_b2   = (const float*)d_in[10];
  const float* enc_ln1g = (const float*)d_in[11];
  const float* enc_ln1b = (const float*)d_in[12];
  const float* enc_ln2g = (const float*)d_in[13];
  const float* enc_ln2b = (const float*)d_in[14];
  const float* enc_lnfg = (const float*)d_in[15];
  const float* enc_lnfb = (const float*)d_in[16];
  const float* dec_tok  = (const float*)d_in[17];
  const float* dec_pos  = (const float*)d_in[18];
  const float* dec_qkv  = (const float*)d_in[19];
  const float* dec_wo   = (const float*)d_in[20];
  const float* dec_bo   = (const float*)d_in[21];
  const float* dec_cqkv = (const float*)d_in[22];
  const float* dec_cwo  = (const float*)d_in[23];
  const float* dec_cbo  = (const float*)d_in[24];
  const float* dec_w1   = (const float*)d_in[25];
  const float* dec_b1   = (const float*)d_in[26];
  const float* dec_w2   = (const float*)d_in[27];
  const float* dec_b2   = (const float*)d_in[28];
  const float* dec_ln1g = (const float*)d_in[29];
  const float* dec_ln1b = (const float*)d_in[30];
  const float* dec_ln2g = (const float*)d_in[31];
  const float* dec_ln2b = (const float*)d_in[32];
  const float* dec_ln3g = (const float*)d_in[33];
  const float* dec_ln3b = (const float*)d_in[34];
  const float* dec_lnfg = (const float*)d_in[35];
  const float* dec_lnfb = (const float*)d_in[36];
  const float* lm_w     = (const float*)d_in[37];
  const float* lm_b     = (const float*)d_in[38];

  constexpr long De2 = (long)Dc * Dc;          // 589824
  constexpr long DF  = (long)Dc * FFc;         // 2359296

  // ---- d_out tail as weight cache: [0,192MiB) scores, then bf16 W^T cache ----
  char* ob = (char*)d_out;
  float* scores = (float*)ob;                                  // 48 * 1M f32 = 192 MiB
  unsigned short* wc = (unsigned short*)(ob + (size_t)Bc * Hc * Tc * Tc * 4);
  size_t woff = 0;
  auto take = [&](size_t n) { unsigned short* p = wc + woff; woff += n; return p; };
  unsigned short* enc_qkvT  = take(18ul * De2);
  unsigned short* enc_woT   = take(6ul * De2);
  unsigned short* enc_w1T   = take(6ul * DF);
  unsigned short* enc_w2T   = take(6ul * DF);
  unsigned short* dec_qkvT  = take(18ul * De2);
  unsigned short* dec_woT   = take(6ul * De2);
  unsigned short* dec_cqkvT = take(18ul * De2);
  unsigned short* dec_cwoT  = take(6ul * De2);
  unsigned short* dec_w1T   = take(6ul * DF);
  unsigned short* dec_w2T   = take(6ul * DF);

  // ---- ws layout (~137 MB) ----
  char* ws = (char*)d_ws;
  const size_t need = (size_t)Dc * Vc * 2 + 2ull * Mtot * Dc * 4 + 3ull * Mtot * Dc * 2 +
                      3ull * Mtot * Dc * 2 + (size_t)Mtot * FFc * 2 + (size_t)Mtot * Dc * 2 +
                      (size_t)Bc * Hc * HDc * Tc * 2 + 4096;
  if (ws_size < need) return;
  auto takeW = [&](size_t bytes) { char* p = ws; ws += (bytes + 255) & ~255ull; return p; };
  unsigned short* lm_wT = (unsigned short*)takeW((size_t)Dc * Vc * 2);
  float* xe             = (float*)takeW((size_t)Mtot * Dc * 4);
  float* xd             = (float*)takeW((size_t)Mtot * Dc * 4);
  unsigned short* hbf   = (unsigned short*)takeW((size_t)Mtot * Dc * 2);
  unsigned short* qkvb  = (unsigned short*)takeW(3ull * Mtot * Dc * 2);
  unsigned short* ao    = (unsigned short*)takeW((size_t)Mtot * Dc * 2);
  unsigned short* mid   = (unsigned short*)takeW((size_t)Mtot * FFc * 2);
  unsigned short* eo    = (unsigned short*)takeW((size_t)Mtot * Dc * 2);
  unsigned short* vT    = (unsigned short*)takeW((size_t)Bc * Hc * HDc * Tc * 2);
  unsigned short* qb = qkvb;
  unsigned short* kb = qkvb + (size_t)Mtot * Dc;
  unsigned short* vb = qkvb + 2ull * Mtot * Dc;

  const dim3 TB(256);

  // ---- weight conversion (f32 [K][N] -> bf16 [N][K]) ----
  wconv_k<<<dim3(Dc/32, Dc/32, 18), TB, 0, stream>>>(enc_qkv, enc_qkvT, Dc, Dc);
  wconv_k<<<dim3(Dc/32, Dc/32,  6), TB, 0, stream>>>(enc_wo,  enc_woT,  Dc, Dc);
  wconv_k<<<dim3(Dc/32, FFc/32, 6), TB, 0, stream>>>(enc_w1,  enc_w1T,  Dc, FFc);
  wconv_k<<<dim3(FFc/32, Dc/32, 6), TB, 0, stream>>>(enc_w2,  enc_w2T,  FFc, Dc);
  wconv_k<<<dim3(Dc/32, Dc/32, 18), TB, 0, stream>>>(dec_qkv, dec_qkvT, Dc, Dc);
  wconv_k<<<dim3(Dc/32, Dc/32,  6), TB, 0, stream>>>(dec_wo,  dec_woT,  Dc, Dc);
  wconv_k<<<dim3(Dc/32, Dc/32, 18), TB, 0, stream>>>(dec_cqkv,dec_cqkvT,Dc, Dc);
  wconv_k<<<dim3(Dc/32, Dc/32,  6), TB, 0, stream>>>(dec_cwo, dec_cwoT, Dc, Dc);
  wconv_k<<<dim3(Dc/32, FFc/32, 6), TB, 0, stream>>>(dec_w1,  dec_w1T,  Dc, FFc);
  wconv_k<<<dim3(FFc/32, Dc/32, 6), TB, 0, stream>>>(dec_w2,  dec_w2T,  FFc, Dc);
  wconv_k<<<dim3(Dc/32, Vc/32,  1), TB, 0, stream>>>(lm_w,    lm_wT,    Dc, Vc);

  auto LN = [&](const float* X, const float* g, const float* b, unsigned short* o) {
    ln_k<<<dim3(Mtot), TB, 0, stream>>>(X, g, b, o);
  };
  auto QKV3 = [&](const unsigned short* Abf, const unsigned short* W3T) {
    gemm_k<128,128,4,4,false,false,false,true><<<dim3(Mtot/128, Dc/128, 3), TB, 0, stream>>>(
        Abf, 0, 0, Dc, W3T, De2, 0, Dc,
        qkvb, (long)Mtot*Dc, 0, Dc, nullptr, nullptr, 0, Dc, 1, 1.f);
  };
  auto PROJ1 = [&](const unsigned short* Abf, const unsigned short* WT, unsigned short* Cb) {
    gemm_k<128,128,4,4,false,false,false,true><<<dim3(Mtot/128, Dc/128, 1), TB, 0, stream>>>(
        Abf, 0, 0, Dc, WT, 0, 0, Dc,
        Cb, 0, 0, Dc, nullptr, nullptr, 0, Dc, 1, 1.f);
  };
  auto KV2 = [&](const unsigned short* Abf, const unsigned short* W2T) {
    gemm_k<128,128,4,4,false,false,false,true><<<dim3(Mtot/128, Dc/128, 2), TB, 0, stream>>>(
        Abf, 0, 0, Dc, W2T, De2, 0, Dc,
        kb, (long)Mtot*Dc, 0, Dc, nullptr, nullptr, 0, Dc, 1, 1.f);
  };
  auto SCORES = [&]() {
    gemm_k<128,128,4,4,false,false,false,false><<<dim3(Tc/128, Tc/128, Bc*Hc), TB, 0, stream>>>(
        qb, (long)Tc*Dc, HDc, Dc,
        kb, (long)Tc*Dc, HDc, Dc,
        scores, (long)Hc*Tc*Tc, (long)Tc*Tc, Tc, nullptr, nullptr, 0, HDc, Hc, 0.125f);
  };
  auto SMAX = [&](bool causal) {
    if (causal) softmax_k<true ><<<dim3(Bc*Hc*Tc), TB, 0, stream>>>(scores);
    else        softmax_k<false><<<dim3(Bc*Hc*Tc), TB, 0, stream>>>(scores);
  };
  auto VT = [&]() {
    vtrans_k<<<dim3(Tc/64, Bc*Hc), TB, 0, stream>>>(vb, vT);
  };
  auto PV = [&]() {
    gemm_k<128,64,4,2,false,false,false,true><<<dim3(Tc/128, 1, Bc*Hc), TB, 0, stream>>>(
        (const unsigned short*)scores, (long)Hc*Tc*2*Tc, (long)Tc*2*Tc, 2*Tc,
        vT, (long)Hc*HDc*Tc, (long)HDc*Tc, Tc,
        ao, (long)Tc*Dc, HDc, Dc, nullptr, nullptr, 0, Tc, Hc, 1.f);
  };
  auto ORES = [&](const unsigned short* Abf, const unsigned short* WT, const float* bias, float* X) {
    gemm_k<128,128,4,4,true,false,true,false><<<dim3(Mtot/128, Dc/128, 1), TB, 0, stream>>>(
        Abf, 0, 0, Dc, WT, 0, 0, Dc,
        X, 0, 0, Dc, bias, X, Dc, Dc, 1, 1.f);
  };
  auto FFN1 = [&](const unsigned short* Abf, const unsigned short* WT, const float* bias) {
    gemm_k<128,128,4,4,true,true,false,true><<<dim3(Mtot/128, FFc/128, 1), TB, 0, stream>>>(
        Abf, 0, 0, Dc, WT, 0, 0, Dc,
        mid, 0, 0, FFc, bias, nullptr, 0, Dc, 1, 1.f);
  };
  auto FFN2 = [&](const unsigned short* WT, const float* bias, float* X) {
    gemm_k<128,128,4,4,true,false,true,false><<<dim3(Mtot/128, Dc/128, 1), TB, 0, stream>>>(
        mid, 0, 0, FFc, WT, 0, 0, FFc,
        X, 0, 0, Dc, bias, X, Dc, FFc, 1, 1.f);
  };

  // ======================= encoder =======================
  embed_k<<<dim3(Mtot), TB, 0, stream>>>(enc_in, enc_tok, enc_pos, xe);
  for (int i = 0; i < Lc; i++) {
    LN(xe, enc_ln1g + i * Dc, enc_ln1b + i * Dc, hbf);
    QKV3(hbf, enc_qkvT + (size_t)i * 3 * De2);
    SCORES(); SMAX(true); VT(); PV();
    ORES(ao, enc_woT + (size_t)i * De2, enc_bo + i * Dc, xe);
    LN(xe, enc_ln2g + i * Dc, enc_ln2b + i * Dc, hbf);
    FFN1(hbf, enc_w1T + (size_t)i * DF, enc_b1 + i * FFc);
    FFN2(enc_w2T + (size_t)i * DF, enc_b2 + i * Dc, xe);
  }
  LN(xe, enc_lnfg, enc_lnfb, eo);

  // ======================= decoder =======================
  embed_k<<<dim3(Mtot), TB, 0, stream>>>(idx, dec_tok, dec_pos, xd);
  for (int i = 0; i < Lc; i++) {
    LN(xd, dec_ln1g + i * Dc, dec_ln1b + i * Dc, hbf);
    QKV3(hbf, dec_qkvT + (size_t)i * 3 * De2);
    SCORES(); SMAX(true); VT(); PV();
    ORES(ao, dec_woT + (size_t)i * De2, dec_bo + i * Dc, xd);
    LN(xd, dec_ln2g + i * Dc, dec_ln2b + i * Dc, hbf);
    PROJ1(hbf, dec_cqkvT + (size_t)i * 3 * De2, qb);
    KV2(eo, dec_cqkvT + (size_t)i * 3 * De2 + De2);
    SCORES(); SMAX(false); VT(); PV();
    ORES(ao, dec_cwoT + (size_t)i * De2, dec_cbo + i * Dc, xd);
    LN(xd, dec_ln3g + i * Dc, dec_ln3b + i * Dc, hbf);
    FFN1(hbf, dec_w1T + (size_t)i * DF, dec_b1 + i * FFc);
    FFN2(dec_w2T + (size_t)i * DF, dec_b2 + i * Dc, xd);
  }
  LN(xd, dec_lnfg, dec_lnfb, hbf);

  // ======================= LM head =======================
  gemm_k<128,128,4,4,true,false,false,false><<<dim3(Mtot/128, Vc/128, 1), TB, 0, stream>>>(
      hbf, 0, 0, Dc, lm_wT, 0, 0, Dc,
      d_out, 0, 0, Vc, lm_b, nullptr, 0, Dc, 1, 1.f);
}

// Round 3
// 4746.948 us; speedup vs baseline: 2.4533x; 1.2471x over previous
//
#include <hip/hip_runtime.h>

// ---------------------------------------------------------------------------
// GPT encoder-decoder forward on MI355X (gfx950).
// Round 3: flash attention (fused QK^T + online softmax + PV), removing the
// materialized 201MB score matrix.  GEMMs unchanged from round 2.
// ---------------------------------------------------------------------------

typedef __bf16 bf16x8 __attribute__((ext_vector_type(8)));
typedef float  f32x4  __attribute__((ext_vector_type(4)));
typedef unsigned short u16x4 __attribute__((ext_vector_type(4)));
typedef unsigned short u16x8 __attribute__((ext_vector_type(8)));

constexpr int Lc = 6, Dc = 768, Hc = 12, HDc = 64, Vc = 32000;
constexpr int Bc = 4, Tc = 1024, FFc = 3072;
constexpr int Mtot = Bc * Tc;  // 4096

static __device__ __forceinline__ unsigned short f2bf(float f) {
  union { float f; unsigned u; } x; x.f = f;
  unsigned r = x.u + 0x7fffu + ((x.u >> 16) & 1u);   // RNE
  return (unsigned short)(r >> 16);
}
static __device__ __forceinline__ float bf2f(unsigned short s) {
  union { unsigned u; float f; } c; c.u = (unsigned)s << 16; return c.f;
}

static __device__ __forceinline__ void gl_lds16(const unsigned short* g, unsigned short* l) {
  __builtin_amdgcn_global_load_lds(
      (const __attribute__((address_space(1))) unsigned int*)g,
      (__attribute__((address_space(3))) unsigned int*)l, 16, 0, 0);
}

// ---------------------------------------------------------------------------
// Block reductions (256 threads = 4 waves)
// ---------------------------------------------------------------------------
static __device__ __forceinline__ float blockReduceSum(float v, float* red) {
  #pragma unroll
  for (int o = 32; o; o >>= 1) v += __shfl_xor(v, o, 64);
  int w = threadIdx.x >> 6;
  __syncthreads();
  if ((threadIdx.x & 63) == 0) red[w] = v;
  __syncthreads();
  return red[0] + red[1] + red[2] + red[3];
}

// ---------------------------------------------------------------------------
// Weight transpose+convert: W f32 [K][N] -> WT bf16 [N][K], batched over z.
// ---------------------------------------------------------------------------
__global__ __launch_bounds__(256) void wconv_k(const float* __restrict__ W,
                                               unsigned short* __restrict__ WT,
                                               int K, int N) {
  __shared__ float t[32][33];
  const long zoff = (long)blockIdx.z * K * N;
  const int k0 = blockIdx.x * 32, n0 = blockIdx.y * 32;
  const int tid = threadIdx.x;
  const int rr = tid >> 3;
  const int cc = (tid & 7) * 4;
  f32x4 v = *reinterpret_cast<const f32x4*>(W + zoff + (long)(k0 + rr) * N + n0 + cc);
  #pragma unroll
  for (int j = 0; j < 4; j++) t[rr][cc + j] = v[j];
  __syncthreads();
  u16x4 o;
  #pragma unroll
  for (int j = 0; j < 4; j++) o[j] = f2bf(t[cc + j][rr]);
  *reinterpret_cast<u16x4*>(WT + zoff + (long)(n0 + rr) * K + k0 + cc) = o;
}

// ---------------------------------------------------------------------------
// V transpose: vb bf16 [B*T][D] (head h cols) -> vT bf16 [B*H][HD][T]
// ---------------------------------------------------------------------------
__global__ __launch_bounds__(256) void vtrans_k(const unsigned short* __restrict__ V,
                                                unsigned short* __restrict__ VT) {
  __shared__ unsigned short t[64][65];
  const int bh = blockIdx.y;
  const int b = bh / Hc, h = bh % Hc;
  const int t0 = blockIdx.x * 64;
  const int tid = threadIdx.x;
  const int rr = tid >> 3;
  const int c8 = (tid & 7) * 8;
  #pragma unroll
  for (int rep = 0; rep < 2; rep++) {
    int row = rep * 32 + rr;
    u16x8 v = *reinterpret_cast<const u16x8*>(V + (long)(b * Tc + t0 + row) * Dc + h * HDc + c8);
    #pragma unroll
    for (int j = 0; j < 8; j++) t[row][c8 + j] = v[j];
  }
  __syncthreads();
  #pragma unroll
  for (int rep = 0; rep < 2; rep++) {
    int hd = rep * 32 + rr;
    u16x8 o;
    #pragma unroll
    for (int j = 0; j < 8; j++) o[j] = t[c8 + j][hd];
    *reinterpret_cast<u16x8*>(VT + ((long)bh * HDc + hd) * Tc + t0 + c8) = o;
  }
}

// ---------------------------------------------------------------------------
// Embedding
// ---------------------------------------------------------------------------
__global__ __launch_bounds__(256) void embed_k(const int* __restrict__ idx,
                                               const float* __restrict__ tok,
                                               const float* __restrict__ pos,
                                               float* __restrict__ out) {
  const long row = blockIdx.x;
  const int t = (int)(row % Tc);
  const long id = idx[row];
  #pragma unroll
  for (int j = 0; j < 3; j++) {
    int e = threadIdx.x + j * 256;
    out[row * Dc + e] = tok[id * Dc + e] + pos[(long)t * Dc + e];
  }
}

// ---------------------------------------------------------------------------
// LayerNorm over D=768, output bf16
// ---------------------------------------------------------------------------
__global__ __launch_bounds__(256) void ln_k(const float* __restrict__ X,
                                            const float* __restrict__ g,
                                            const float* __restrict__ bta,
                                            unsigned short* __restrict__ out) {
  __shared__ float red[4];
  const long row = blockIdx.x;
  const int tid = threadIdx.x;
  float v[3];
  #pragma unroll
  for (int j = 0; j < 3; j++) v[j] = X[row * Dc + tid + j * 256];
  float s = v[0] + v[1] + v[2];
  s = blockReduceSum(s, red);
  float mean = s * (1.f / 768.f);
  float q = 0.f;
  #pragma unroll
  for (int j = 0; j < 3; j++) { float d = v[j] - mean; q += d * d; }
  q = blockReduceSum(q, red);
  float rstd = rsqrtf(q * (1.f / 768.f) + 1e-5f);
  #pragma unroll
  for (int j = 0; j < 3; j++) {
    int e = tid + j * 256;
    out[row * Dc + e] = f2bf((v[j] - mean) * rstd * g[e] + bta[e]);
  }
}

// ---------------------------------------------------------------------------
// Flash attention.  Per block: 128 Q rows of one (b,h); 4 waves x 32 rows.
// K chunks of 128; K tile [128][64] and V^T tile [64][128] staged via
// global_load_lds with XOR-swizzled source; P through per-wave swizzled LDS.
// Q,K from bf16 [B*T][Dc] (head col slice); V^T from vT [B*H][HD][T];
// O (bf16) into ao rows.  Scores scaled by 0.125 (folded into Q, exact).
// ---------------------------------------------------------------------------
template <bool CAUSAL>
__global__ __launch_bounds__(256) void flash_k(
    const unsigned short* __restrict__ Q,
    const unsigned short* __restrict__ K,
    const unsigned short* __restrict__ VT,
    unsigned short* __restrict__ O) {
  __shared__ __align__(16) unsigned short Ks[128 * 64];
  __shared__ __align__(16) unsigned short Vs[64 * 128];
  __shared__ __align__(16) unsigned short Ps[4][32 * 128];

  const int tid = threadIdx.x;
  const int lane = tid & 63;
  const int w = tid >> 6;
  const int lane16 = lane & 15;
  const int l4 = lane >> 4;
  const int bh = blockIdx.y;
  const int b = bh / Hc, h = bh % Hc;
  const int q0 = blockIdx.x * 128;

  const unsigned short* Qb = Q + ((long)b * Tc) * Dc + h * HDc;
  const unsigned short* Kb = K + ((long)b * Tc) * Dc + h * HDc;
  const unsigned short* Vb = VT + (long)bh * HDc * Tc;
  unsigned short* Ob = O + ((long)b * Tc) * Dc + h * HDc;

  // ---- Q fragments in registers, pre-scaled by 0.125 (exact in bf16) ----
  bf16x8 qf[2][2];
  #pragma unroll
  for (int m = 0; m < 2; m++)
    #pragma unroll
    for (int kk = 0; kk < 2; kk++) {
      u16x8 raw = *reinterpret_cast<const u16x8*>(
          Qb + (long)(q0 + w * 32 + m * 16 + lane16) * Dc + kk * 32 + l4 * 8);
      bf16x8 f;
      #pragma unroll
      for (int j = 0; j < 8; j++) f[j] = (__bf16)(bf2f(raw[j]) * 0.125f);
      qf[m][kk] = f;
    }

  float mrow[2][4], lrow[2][4];
  f32x4 accO[2][4];
  #pragma unroll
  for (int m = 0; m < 2; m++)
    #pragma unroll
    for (int r = 0; r < 4; r++) { mrow[m][r] = -1e30f; lrow[m][r] = 0.f; }
  #pragma unroll
  for (int m = 0; m < 2; m++)
    #pragma unroll
    for (int d4 = 0; d4 < 4; d4++)
      #pragma unroll
      for (int r = 0; r < 4; r++) accO[m][d4][r] = 0.f;

  const int nch = CAUSAL ? (blockIdx.x + 1) : (Tc / 128);
  for (int c = 0; c < nch; c++) {
    const int k0 = c * 128;
    __syncthreads();
    // ---- stage K tile (16KB) and V^T tile (16KB) ----
    #pragma unroll
    for (int it = 0; it < 4; it++) {
      int u = (it * 4 + w) * 64 + lane;
      int r = u >> 3, s = u & 7;                    // K: 128 rows x 8 slots
      gl_lds16(Kb + (long)(k0 + r) * Dc + ((s ^ (r & 7)) * 8), &Ks[(it * 4 + w) * 512]);
      int r2 = u >> 4, s2 = u & 15;                 // V^T: 64 rows x 16 slots
      gl_lds16(Vb + (long)r2 * Tc + k0 + ((s2 ^ (r2 & 7)) * 8), &Vs[(it * 4 + w) * 512]);
    }
    __syncthreads();

    // ---- S = Q K^T (wave's 32 x 128) ----
    f32x4 sacc[2][8];
    #pragma unroll
    for (int m = 0; m < 2; m++)
      #pragma unroll
      for (int n = 0; n < 8; n++)
        #pragma unroll
        for (int r = 0; r < 4; r++) sacc[m][n][r] = 0.f;
    #pragma unroll
    for (int n = 0; n < 8; n++) {
      int row = n * 16 + lane16;
      #pragma unroll
      for (int kk = 0; kk < 2; kk++) {
        bf16x8 kf = *reinterpret_cast<const bf16x8*>(
            &Ks[row * 64 + (((kk * 4 + l4) ^ (row & 7)) * 8)]);
        sacc[0][n] = __builtin_amdgcn_mfma_f32_16x16x32_bf16(qf[0][kk], kf, sacc[0][n], 0, 0, 0);
        sacc[1][n] = __builtin_amdgcn_mfma_f32_16x16x32_bf16(qf[1][kk], kf, sacc[1][n], 0, 0, 0);
      }
    }

    // ---- causal mask on the diagonal chunk ----
    if (CAUSAL && c == nch - 1) {
      #pragma unroll
      for (int m = 0; m < 2; m++)
        #pragma unroll
        for (int n = 0; n < 8; n++)
          #pragma unroll
          for (int r = 0; r < 4; r++) {
            int kcol = k0 + n * 16 + lane16;
            int q = q0 + w * 32 + m * 16 + l4 * 4 + r;
            if (kcol > q) sacc[m][n][r] = -1e30f;
          }
    }

    // ---- online softmax; write P (bf16) to per-wave swizzled LDS ----
    #pragma unroll
    for (int m = 0; m < 2; m++)
      #pragma unroll
      for (int r = 0; r < 4; r++) {
        float smax = sacc[m][0][r];
        #pragma unroll
        for (int n = 1; n < 8; n++) smax = fmaxf(smax, sacc[m][n][r]);
        #pragma unroll
        for (int off = 1; off < 16; off <<= 1) smax = fmaxf(smax, __shfl_xor(smax, off, 64));
        float mold = mrow[m][r];
        float mnew = fmaxf(mold, smax);
        float sc = __expf(mold - mnew);
        float psum = 0.f;
        unsigned short pv[8];
        #pragma unroll
        for (int n = 0; n < 8; n++) {
          float p = __expf(sacc[m][n][r] - mnew);
          psum += p;
          pv[n] = f2bf(p);
        }
        #pragma unroll
        for (int off = 1; off < 16; off <<= 1) psum += __shfl_xor(psum, off, 64);
        lrow[m][r] = lrow[m][r] * sc + psum;
        mrow[m][r] = mnew;
        #pragma unroll
        for (int d4 = 0; d4 < 4; d4++) accO[m][d4][r] *= sc;
        int prow = m * 16 + l4 * 4 + r;
        #pragma unroll
        for (int n = 0; n < 8; n++) {
          int col = n * 16 + lane16;
          Ps[w][prow * 128 + (((col >> 3) ^ (prow & 7)) * 8) + (col & 7)] = pv[n];
        }
      }

    // ---- O += P V  (A-frags from Ps, B-frags from Vs) ----
    #pragma unroll
    for (int kk = 0; kk < 4; kk++) {
      bf16x8 pa[2];
      #pragma unroll
      for (int m = 0; m < 2; m++) {
        int arow = m * 16 + lane16;
        pa[m] = *reinterpret_cast<const bf16x8*>(
            &Ps[w][arow * 128 + (((kk * 4 + l4) ^ (arow & 7)) * 8)]);
      }
      #pragma unroll
      for (int d4 = 0; d4 < 4; d4++) {
        int vrow = d4 * 16 + lane16;
        bf16x8 vf = *reinterpret_cast<const bf16x8*>(
            &Vs[vrow * 128 + (((kk * 4 + l4) ^ (vrow & 7)) * 8)]);
        accO[0][d4] = __builtin_amdgcn_mfma_f32_16x16x32_bf16(pa[0], vf, accO[0][d4], 0, 0, 0);
        accO[1][d4] = __builtin_amdgcn_mfma_f32_16x16x32_bf16(pa[1], vf, accO[1][d4], 0, 0, 0);
      }
    }
  }

  // ---- normalize and store O ----
  #pragma unroll
  for (int m = 0; m < 2; m++)
    #pragma unroll
    for (int r = 0; r < 4; r++) {
      float inv = 1.f / lrow[m][r];
      int q = q0 + w * 32 + m * 16 + l4 * 4 + r;
      #pragma unroll
      for (int d4 = 0; d4 < 4; d4++)
        Ob[(long)q * Dc + d4 * 16 + lane16] = f2bf(accO[m][d4][r] * inv);
    }
}

// ---------------------------------------------------------------------------
// MFMA GEMM, m97 structure (unchanged from round 2).
// ---------------------------------------------------------------------------
template <int BM, int BN, int MF, int NF, bool HASBIAS, bool RELU, bool HASRES, bool OUTBF>
__global__ __launch_bounds__(256) void gemm_k(
    const unsigned short* __restrict__ A, long sAb, long sAh, int lda,
    const unsigned short* __restrict__ BT, long sBb, long sBh, int ldb,
    void* Cp, long sCb, long sCh, int ldc,
    const float* __restrict__ bias,
    const float* __restrict__ Res, int ldr,
    int K, int nH, float alpha) {
  constexpr int BK = 32;
  __shared__ __align__(16) unsigned short Asm[BM * BK];
  __shared__ __align__(16) unsigned short Bsm[BN * BK];

  const int tid = threadIdx.x;
  const int lane = tid & 63;
  const int w = tid >> 6;
  const int wr = w >> 1, wc = w & 1;
  const int lane16 = lane & 15;

  const int z = blockIdx.z;
  const int bb = z / nH, hh = z % nH;
  const long offA = sAb * bb + sAh * hh;
  const long offB = sBb * bb + sBh * hh;
  const long offC = sCb * bb + sCh * hh;

  const int m0 = blockIdx.x * BM;
  const int n0 = blockIdx.y * BN;

  const int srow = lane >> 2;
  const int g8 = (((lane & 3) ^ ((lane >> 3) & 3)) * 8);
  const int kslot = ((lane >> 4) ^ ((lane16 >> 1) & 3)) * 8;

  const unsigned short* Ab = A + offA + (long)m0 * lda;
  const unsigned short* Bb = BT + offB + (long)n0 * ldb;

  const unsigned short* aP[BM / 64];
  #pragma unroll
  for (int j = 0; j < BM / 64; j++)
    aP[j] = Ab + (long)(w * (BM / 4) + j * 16 + srow) * lda + g8;
  const unsigned short* bP[BN / 64];
  #pragma unroll
  for (int j = 0; j < BN / 64; j++)
    bP[j] = Bb + (long)(w * (BN / 4) + j * 16 + srow) * ldb + g8;

  f32x4 acc[MF][NF];
  #pragma unroll
  for (int m = 0; m < MF; m++)
    #pragma unroll
    for (int n = 0; n < NF; n++)
      #pragma unroll
      for (int r = 0; r < 4; r++) acc[m][n][r] = 0.f;

  for (int k0 = 0; k0 < K; k0 += BK) {
    __syncthreads();
    #pragma unroll
    for (int j = 0; j < BM / 64; j++)
      gl_lds16(aP[j] + k0, &Asm[(w * (BM / 4) + j * 16) * BK]);
    #pragma unroll
    for (int j = 0; j < BN / 64; j++)
      gl_lds16(bP[j] + k0, &Bsm[(w * (BN / 4) + j * 16) * BK]);
    __syncthreads();

    bf16x8 af[MF], bfr[NF];
    #pragma unroll
    for (int m = 0; m < MF; m++)
      af[m] = *reinterpret_cast<const bf16x8*>(&Asm[(wr * MF * 16 + m * 16 + lane16) * BK + kslot]);
    #pragma unroll
    for (int n = 0; n < NF; n++)
      bfr[n] = *reinterpret_cast<const bf16x8*>(&Bsm[(wc * NF * 16 + n * 16 + lane16) * BK + kslot]);
    #pragma unroll
    for (int m = 0; m < MF; m++)
      #pragma unroll
      for (int n = 0; n < NF; n++)
        acc[m][n] = __builtin_amdgcn_mfma_f32_16x16x32_bf16(af[m], bfr[n], acc[m][n], 0, 0, 0);
  }

  const int r0 = m0 + wr * MF * 16;
  const int c0 = n0 + wc * NF * 16;
  #pragma unroll
  for (int m = 0; m < MF; m++) {
    #pragma unroll
    for (int n = 0; n < NF; n++) {
      #pragma unroll
      for (int r = 0; r < 4; r++) {
        int rr = r0 + m * 16 + (lane >> 4) * 4 + r;
        int cc = c0 + n * 16 + lane16;
        float v = acc[m][n][r] * alpha;
        if constexpr (HASBIAS) v += bias[cc];
        if constexpr (RELU) v = fmaxf(v, 0.f);
        if constexpr (HASRES) v += Res[offC + (long)rr * ldr + cc];
        if constexpr (OUTBF) ((unsigned short*)Cp)[offC + (long)rr * ldc + cc] = f2bf(v);
        else                 ((float*)Cp)[offC + (long)rr * ldc + cc] = v;
      }
    }
  }
}

// ---------------------------------------------------------------------------
extern "C" void kernel_launch(void* const* d_in, const int* in_sizes, int n_in,
                              void* d_out, int out_size, void* d_ws, size_t ws_size,
                              hipStream_t stream) {
  (void)in_sizes; (void)n_in; (void)out_size;

  const int*   idx      = (const int*)d_in[0];
  const int*   enc_in   = (const int*)d_in[1];
  const float* enc_tok  = (const float*)d_in[2];
  const float* enc_pos  = (const float*)d_in[3];
  const float* enc_qkv  = (const float*)d_in[4];
  const float* enc_wo   = (const float*)d_in[5];
  const float* enc_bo   = (const float*)d_in[6];
  const float* enc_w1   = (const float*)d_in[7];
  const float* enc_b1   = (const float*)d_in[8];
  const float* enc_w2   = (const float*)d_in[9];
  const float* enc_b2   = (const float*)d_in[10];
  const float* enc_ln1g = (const float*)d_in[11];
  const float* enc_ln1b = (const float*)d_in[12];
  const float* enc_ln2g = (const float*)d_in[13];
  const float* enc_ln2b = (const float*)d_in[14];
  const float* enc_lnfg = (const float*)d_in[15];
  const float* enc_lnfb = (const float*)d_in[16];
  const float* dec_tok  = (const float*)d_in[17];
  const float* dec_pos  = (const float*)d_in[18];
  const float* dec_qkv  = (const float*)d_in[19];
  const float* dec_wo   = (const float*)d_in[20];
  const float* dec_bo   = (const float*)d_in[21];
  const float* dec_cqkv = (const float*)d_in[22];
  const float* dec_cwo  = (const float*)d_in[23];
  const float* dec_cbo  = (const float*)d_in[24];
  const float* dec_w1   = (const float*)d_in[25];
  const float* dec_b1   = (const float*)d_in[26];
  const float* dec_w2   = (const float*)d_in[27];
  const float* dec_b2   = (const float*)d_in[28];
  const float* dec_ln1g = (const float*)d_in[29];
  const float* dec_ln1b = (const float*)d_in[30];
  const float* dec_ln2g = (const float*)d_in[31];
  const float* dec_ln2b = (const float*)d_in[32];
  const float* dec_ln3g = (const float*)d_in[33];
  const float* dec_ln3b = (const float*)d_in[34];
  const float* dec_lnfg = (const float*)d_in[35];
  const float* dec_lnfb = (const float*)d_in[36];
  const float* lm_w     = (const float*)d_in[37];
  const float* lm_b     = (const float*)d_in[38];

  constexpr long De2 = (long)Dc * Dc;
  constexpr long DF  = (long)Dc * FFc;

  // ---- d_out head as weight cache (rewritten every call; LM head writes last) ----
  unsigned short* wcache = (unsigned short*)d_out;
  size_t woff = 0;
  auto take = [&](size_t n) { unsigned short* p = wcache + woff; woff += n; return p; };
  unsigned short* enc_qkvT  = take(18ul * De2);
  unsigned short* enc_woT   = take(6ul * De2);
  unsigned short* enc_w1T   = take(6ul * DF);
  unsigned short* enc_w2T   = take(6ul * DF);
  unsigned short* dec_qkvT  = take(18ul * De2);
  unsigned short* dec_woT   = take(6ul * De2);
  unsigned short* dec_cqkvT = take(18ul * De2);
  unsigned short* dec_cwoT  = take(6ul * De2);
  unsigned short* dec_w1T   = take(6ul * DF);
  unsigned short* dec_w2T   = take(6ul * DF);

  // ---- ws layout ----
  char* ws = (char*)d_ws;
  const size_t need = (size_t)Dc * Vc * 2 + 2ull * Mtot * Dc * 4 + 3ull * Mtot * Dc * 2 +
                      3ull * Mtot * Dc * 2 + (size_t)Mtot * FFc * 2 + (size_t)Mtot * Dc * 2 +
                      (size_t)Bc * Hc * HDc * Tc * 2 + 4096;
  if (ws_size < need) return;
  auto takeW = [&](size_t bytes) { char* p = ws; ws += (bytes + 255) & ~255ull; return p; };
  unsigned short* lm_wT = (unsigned short*)takeW((size_t)Dc * Vc * 2);
  float* xe             = (float*)takeW((size_t)Mtot * Dc * 4);
  float* xd             = (float*)takeW((size_t)Mtot * Dc * 4);
  unsigned short* hbf   = (unsigned short*)takeW((size_t)Mtot * Dc * 2);
  unsigned short* qkvb  = (unsigned short*)takeW(3ull * Mtot * Dc * 2);
  unsigned short* ao    = (unsigned short*)takeW((size_t)Mtot * Dc * 2);
  unsigned short* mid   = (unsigned short*)takeW((size_t)Mtot * FFc * 2);
  unsigned short* eo    = (unsigned short*)takeW((size_t)Mtot * Dc * 2);
  unsigned short* vT    = (unsigned short*)takeW((size_t)Bc * Hc * HDc * Tc * 2);
  unsigned short* qb = qkvb;
  unsigned short* kb = qkvb + (size_t)Mtot * Dc;
  unsigned short* vb = qkvb + 2ull * Mtot * Dc;

  const dim3 TB(256);

  // ---- weight conversion ----
  wconv_k<<<dim3(Dc/32, Dc/32, 18), TB, 0, stream>>>(enc_qkv, enc_qkvT, Dc, Dc);
  wconv_k<<<dim3(Dc/32, Dc/32,  6), TB, 0, stream>>>(enc_wo,  enc_woT,  Dc, Dc);
  wconv_k<<<dim3(Dc/32, FFc/32, 6), TB, 0, stream>>>(enc_w1,  enc_w1T,  Dc, FFc);
  wconv_k<<<dim3(FFc/32, Dc/32, 6), TB, 0, stream>>>(enc_w2,  enc_w2T,  FFc, Dc);
  wconv_k<<<dim3(Dc/32, Dc/32, 18), TB, 0, stream>>>(dec_qkv, dec_qkvT, Dc, Dc);
  wconv_k<<<dim3(Dc/32, Dc/32,  6), TB, 0, stream>>>(dec_wo,  dec_woT,  Dc, Dc);
  wconv_k<<<dim3(Dc/32, Dc/32, 18), TB, 0, stream>>>(dec_cqkv,dec_cqkvT,Dc, Dc);
  wconv_k<<<dim3(Dc/32, Dc/32,  6), TB, 0, stream>>>(dec_cwo, dec_cwoT, Dc, Dc);
  wconv_k<<<dim3(Dc/32, FFc/32, 6), TB, 0, stream>>>(dec_w1,  dec_w1T,  Dc, FFc);
  wconv_k<<<dim3(FFc/32, Dc/32, 6), TB, 0, stream>>>(dec_w2,  dec_w2T,  FFc, Dc);
  wconv_k<<<dim3(Dc/32, Vc/32,  1), TB, 0, stream>>>(lm_w,    lm_wT,    Dc, Vc);

  auto LN = [&](const float* X, const float* g, const float* b, unsigned short* o) {
    ln_k<<<dim3(Mtot), TB, 0, stream>>>(X, g, b, o);
  };
  auto QKV3 = [&](const unsigned short* Abf, const unsigned short* W3T) {
    gemm_k<128,128,4,4,false,false,false,true><<<dim3(Mtot/128, Dc/128, 3), TB, 0, stream>>>(
        Abf, 0, 0, Dc, W3T, De2, 0, Dc,
        qkvb, (long)Mtot*Dc, 0, Dc, nullptr, nullptr, 0, Dc, 1, 1.f);
  };
  auto PROJ1 = [&](const unsigned short* Abf, const unsigned short* WT, unsigned short* Cb) {
    gemm_k<128,128,4,4,false,false,false,true><<<dim3(Mtot/128, Dc/128, 1), TB, 0, stream>>>(
        Abf, 0, 0, Dc, WT, 0, 0, Dc,
        Cb, 0, 0, Dc, nullptr, nullptr, 0, Dc, 1, 1.f);
  };
  auto KV2 = [&](const unsigned short* Abf, const unsigned short* W2T) {
    gemm_k<128,128,4,4,false,false,false,true><<<dim3(Mtot/128, Dc/128, 2), TB, 0, stream>>>(
        Abf, 0, 0, Dc, W2T, De2, 0, Dc,
        kb, (long)Mtot*Dc, 0, Dc, nullptr, nullptr, 0, Dc, 1, 1.f);
  };
  auto VT = [&]() {
    vtrans_k<<<dim3(Tc/64, Bc*Hc), TB, 0, stream>>>(vb, vT);
  };
  auto FLASH = [&](bool causal) {
    if (causal) flash_k<true ><<<dim3(Tc/128, Bc*Hc), TB, 0, stream>>>(qb, kb, vT, ao);
    else        flash_k<false><<<dim3(Tc/128, Bc*Hc), TB, 0, stream>>>(qb, kb, vT, ao);
  };
  auto ORES = [&](const unsigned short* Abf, const unsigned short* WT, const float* bias, float* X) {
    gemm_k<128,128,4,4,true,false,true,false><<<dim3(Mtot/128, Dc/128, 1), TB, 0, stream>>>(
        Abf, 0, 0, Dc, WT, 0, 0, Dc,
        X, 0, 0, Dc, bias, X, Dc, Dc, 1, 1.f);
  };
  auto FFN1 = [&](const unsigned short* Abf, const unsigned short* WT, const float* bias) {
    gemm_k<128,128,4,4,true,true,false,true><<<dim3(Mtot/128, FFc/128, 1), TB, 0, stream>>>(
        Abf, 0, 0, Dc, WT, 0, 0, Dc,
        mid, 0, 0, FFc, bias, nullptr, 0, Dc, 1, 1.f);
  };
  auto FFN2 = [&](const unsigned short* WT, const float* bias, float* X) {
    gemm_k<128,128,4,4,true,false,true,false><<<dim3(Mtot/128, Dc/128, 1), TB, 0, stream>>>(
        mid, 0, 0, FFc, WT, 0, 0, FFc,
        X, 0, 0, Dc, bias, X, Dc, FFc, 1, 1.f);
  };

  // ======================= encoder =======================
  embed_k<<<dim3(Mtot), TB, 0, stream>>>(enc_in, enc_tok, enc_pos, xe);
  for (int i = 0; i < Lc; i++) {
    LN(xe, enc_ln1g + i * Dc, enc_ln1b + i * Dc, hbf);
    QKV3(hbf, enc_qkvT + (size_t)i * 3 * De2);
    VT(); FLASH(true);
    ORES(ao, enc_woT + (size_t)i * De2, enc_bo + i * Dc, xe);
    LN(xe, enc_ln2g + i * Dc, enc_ln2b + i * Dc, hbf);
    FFN1(hbf, enc_w1T + (size_t)i * DF, enc_b1 + i * FFc);
    FFN2(enc_w2T + (size_t)i * DF, enc_b2 + i * Dc, xe);
  }
  LN(xe, enc_lnfg, enc_lnfb, eo);

  // ======================= decoder =======================
  embed_k<<<dim3(Mtot), TB, 0, stream>>>(idx, dec_tok, dec_pos, xd);
  for (int i = 0; i < Lc; i++) {
    LN(xd, dec_ln1g + i * Dc, dec_ln1b + i * Dc, hbf);
    QKV3(hbf, dec_qkvT + (size_t)i * 3 * De2);
    VT(); FLASH(true);
    ORES(ao, dec_woT + (size_t)i * De2, dec_bo + i * Dc, xd);
    LN(xd, dec_ln2g + i * Dc, dec_ln2b + i * Dc, hbf);
    PROJ1(hbf, dec_cqkvT + (size_t)i * 3 * De2, qb);
    KV2(eo, dec_cqkvT + (size_t)i * 3 * De2 + De2);
    VT(); FLASH(false);
    ORES(ao, dec_cwoT + (size_t)i * De2, dec_cbo + i * Dc, xd);
    LN(xd, dec_ln3g + i * Dc, dec_ln3b + i * Dc, hbf);
    FFN1(hbf, dec_w1T + (size_t)i * DF, dec_b1 + i * FFc);
    FFN2(dec_w2T + (size_t)i * DF, dec_b2 + i * Dc, xd);
  }
  LN(xd, dec_lnfg, dec_lnfb, hbf);

  // ======================= LM head =======================
  gemm_k<128,128,4,4,true,false,false,false><<<dim3(Mtot/128, Vc/128, 1), TB, 0, stream>>>(
      hbf, 0, 0, Dc, lm_wT, 0, 0, Dc,
      d_out, 0, 0, Vc, lm_b, nullptr, 0, Dc, 1, 1.f);
}

// Round 4
// 3935.830 us; speedup vs baseline: 2.9589x; 1.2061x over previous
//
#include <hip/hip_runtime.h>

// ---------------------------------------------------------------------------
// GPT encoder-decoder forward on MI355X (gfx950).
// Round 4: 2-phase double-buffered GEMM (BK=64, prefetch-before-compute,
// one barrier per K-step) + BN=64 tile variant to fill the grid on N=768.
// ---------------------------------------------------------------------------

typedef __bf16 bf16x8 __attribute__((ext_vector_type(8)));
typedef float  f32x4  __attribute__((ext_vector_type(4)));
typedef unsigned short u16x4 __attribute__((ext_vector_type(4)));
typedef unsigned short u16x8 __attribute__((ext_vector_type(8)));

constexpr int Lc = 6, Dc = 768, Hc = 12, HDc = 64, Vc = 32000;
constexpr int Bc = 4, Tc = 1024, FFc = 3072;
constexpr int Mtot = Bc * Tc;  // 4096

static __device__ __forceinline__ unsigned short f2bf(float f) {
  union { float f; unsigned u; } x; x.f = f;
  unsigned r = x.u + 0x7fffu + ((x.u >> 16) & 1u);   // RNE
  return (unsigned short)(r >> 16);
}
static __device__ __forceinline__ float bf2f(unsigned short s) {
  union { unsigned u; float f; } c; c.u = (unsigned)s << 16; return c.f;
}

static __device__ __forceinline__ void gl_lds16(const unsigned short* g, unsigned short* l) {
  __builtin_amdgcn_global_load_lds(
      (const __attribute__((address_space(1))) unsigned int*)g,
      (__attribute__((address_space(3))) unsigned int*)l, 16, 0, 0);
}

// ---------------------------------------------------------------------------
// Block reductions (256 threads = 4 waves)
// ---------------------------------------------------------------------------
static __device__ __forceinline__ float blockReduceSum(float v, float* red) {
  #pragma unroll
  for (int o = 32; o; o >>= 1) v += __shfl_xor(v, o, 64);
  int w = threadIdx.x >> 6;
  __syncthreads();
  if ((threadIdx.x & 63) == 0) red[w] = v;
  __syncthreads();
  return red[0] + red[1] + red[2] + red[3];
}

// ---------------------------------------------------------------------------
// Weight transpose+convert: W f32 [K][N] -> WT bf16 [N][K], batched over z.
// ---------------------------------------------------------------------------
__global__ __launch_bounds__(256) void wconv_k(const float* __restrict__ W,
                                               unsigned short* __restrict__ WT,
                                               int K, int N) {
  __shared__ float t[32][33];
  const long zoff = (long)blockIdx.z * K * N;
  const int k0 = blockIdx.x * 32, n0 = blockIdx.y * 32;
  const int tid = threadIdx.x;
  const int rr = tid >> 3;
  const int cc = (tid & 7) * 4;
  f32x4 v = *reinterpret_cast<const f32x4*>(W + zoff + (long)(k0 + rr) * N + n0 + cc);
  #pragma unroll
  for (int j = 0; j < 4; j++) t[rr][cc + j] = v[j];
  __syncthreads();
  u16x4 o;
  #pragma unroll
  for (int j = 0; j < 4; j++) o[j] = f2bf(t[cc + j][rr]);
  *reinterpret_cast<u16x4*>(WT + zoff + (long)(n0 + rr) * K + k0 + cc) = o;
}

// ---------------------------------------------------------------------------
// V transpose: vb bf16 [B*T][D] (head h cols) -> vT bf16 [B*H][HD][T]
// ---------------------------------------------------------------------------
__global__ __launch_bounds__(256) void vtrans_k(const unsigned short* __restrict__ V,
                                                unsigned short* __restrict__ VT) {
  __shared__ unsigned short t[64][65];
  const int bh = blockIdx.y;
  const int b = bh / Hc, h = bh % Hc;
  const int t0 = blockIdx.x * 64;
  const int tid = threadIdx.x;
  const int rr = tid >> 3;
  const int c8 = (tid & 7) * 8;
  #pragma unroll
  for (int rep = 0; rep < 2; rep++) {
    int row = rep * 32 + rr;
    u16x8 v = *reinterpret_cast<const u16x8*>(V + (long)(b * Tc + t0 + row) * Dc + h * HDc + c8);
    #pragma unroll
    for (int j = 0; j < 8; j++) t[row][c8 + j] = v[j];
  }
  __syncthreads();
  #pragma unroll
  for (int rep = 0; rep < 2; rep++) {
    int hd = rep * 32 + rr;
    u16x8 o;
    #pragma unroll
    for (int j = 0; j < 8; j++) o[j] = t[c8 + j][hd];
    *reinterpret_cast<u16x8*>(VT + ((long)bh * HDc + hd) * Tc + t0 + c8) = o;
  }
}

// ---------------------------------------------------------------------------
// Embedding
// ---------------------------------------------------------------------------
__global__ __launch_bounds__(256) void embed_k(const int* __restrict__ idx,
                                               const float* __restrict__ tok,
                                               const float* __restrict__ pos,
                                               float* __restrict__ out) {
  const long row = blockIdx.x;
  const int t = (int)(row % Tc);
  const long id = idx[row];
  #pragma unroll
  for (int j = 0; j < 3; j++) {
    int e = threadIdx.x + j * 256;
    out[row * Dc + e] = tok[id * Dc + e] + pos[(long)t * Dc + e];
  }
}

// ---------------------------------------------------------------------------
// LayerNorm over D=768, output bf16
// ---------------------------------------------------------------------------
__global__ __launch_bounds__(256) void ln_k(const float* __restrict__ X,
                                            const float* __restrict__ g,
                                            const float* __restrict__ bta,
                                            unsigned short* __restrict__ out) {
  __shared__ float red[4];
  const long row = blockIdx.x;
  const int tid = threadIdx.x;
  float v[3];
  #pragma unroll
  for (int j = 0; j < 3; j++) v[j] = X[row * Dc + tid + j * 256];
  float s = v[0] + v[1] + v[2];
  s = blockReduceSum(s, red);
  float mean = s * (1.f / 768.f);
  float q = 0.f;
  #pragma unroll
  for (int j = 0; j < 3; j++) { float d = v[j] - mean; q += d * d; }
  q = blockReduceSum(q, red);
  float rstd = rsqrtf(q * (1.f / 768.f) + 1e-5f);
  #pragma unroll
  for (int j = 0; j < 3; j++) {
    int e = tid + j * 256;
    out[row * Dc + e] = f2bf((v[j] - mean) * rstd * g[e] + bta[e]);
  }
}

// ---------------------------------------------------------------------------
// Flash attention (unchanged from round 3).
// ---------------------------------------------------------------------------
template <bool CAUSAL>
__global__ __launch_bounds__(256) void flash_k(
    const unsigned short* __restrict__ Q,
    const unsigned short* __restrict__ K,
    const unsigned short* __restrict__ VT,
    unsigned short* __restrict__ O) {
  __shared__ __align__(16) unsigned short Ks[128 * 64];
  __shared__ __align__(16) unsigned short Vs[64 * 128];
  __shared__ __align__(16) unsigned short Ps[4][32 * 128];

  const int tid = threadIdx.x;
  const int lane = tid & 63;
  const int w = tid >> 6;
  const int lane16 = lane & 15;
  const int l4 = lane >> 4;
  const int bh = blockIdx.y;
  const int b = bh / Hc, h = bh % Hc;
  const int q0 = blockIdx.x * 128;

  const unsigned short* Qb = Q + ((long)b * Tc) * Dc + h * HDc;
  const unsigned short* Kb = K + ((long)b * Tc) * Dc + h * HDc;
  const unsigned short* Vb = VT + (long)bh * HDc * Tc;
  unsigned short* Ob = O + ((long)b * Tc) * Dc + h * HDc;

  bf16x8 qf[2][2];
  #pragma unroll
  for (int m = 0; m < 2; m++)
    #pragma unroll
    for (int kk = 0; kk < 2; kk++) {
      u16x8 raw = *reinterpret_cast<const u16x8*>(
          Qb + (long)(q0 + w * 32 + m * 16 + lane16) * Dc + kk * 32 + l4 * 8);
      bf16x8 f;
      #pragma unroll
      for (int j = 0; j < 8; j++) f[j] = (__bf16)(bf2f(raw[j]) * 0.125f);
      qf[m][kk] = f;
    }

  float mrow[2][4], lrow[2][4];
  f32x4 accO[2][4];
  #pragma unroll
  for (int m = 0; m < 2; m++)
    #pragma unroll
    for (int r = 0; r < 4; r++) { mrow[m][r] = -1e30f; lrow[m][r] = 0.f; }
  #pragma unroll
  for (int m = 0; m < 2; m++)
    #pragma unroll
    for (int d4 = 0; d4 < 4; d4++)
      #pragma unroll
      for (int r = 0; r < 4; r++) accO[m][d4][r] = 0.f;

  const int nch = CAUSAL ? (blockIdx.x + 1) : (Tc / 128);
  for (int c = 0; c < nch; c++) {
    const int k0 = c * 128;
    __syncthreads();
    #pragma unroll
    for (int it = 0; it < 4; it++) {
      int u = (it * 4 + w) * 64 + lane;
      int r = u >> 3, s = u & 7;
      gl_lds16(Kb + (long)(k0 + r) * Dc + ((s ^ (r & 7)) * 8), &Ks[(it * 4 + w) * 512]);
      int r2 = u >> 4, s2 = u & 15;
      gl_lds16(Vb + (long)r2 * Tc + k0 + ((s2 ^ (r2 & 7)) * 8), &Vs[(it * 4 + w) * 512]);
    }
    __syncthreads();

    f32x4 sacc[2][8];
    #pragma unroll
    for (int m = 0; m < 2; m++)
      #pragma unroll
      for (int n = 0; n < 8; n++)
        #pragma unroll
        for (int r = 0; r < 4; r++) sacc[m][n][r] = 0.f;
    #pragma unroll
    for (int n = 0; n < 8; n++) {
      int row = n * 16 + lane16;
      #pragma unroll
      for (int kk = 0; kk < 2; kk++) {
        bf16x8 kf = *reinterpret_cast<const bf16x8*>(
            &Ks[row * 64 + (((kk * 4 + l4) ^ (row & 7)) * 8)]);
        sacc[0][n] = __builtin_amdgcn_mfma_f32_16x16x32_bf16(qf[0][kk], kf, sacc[0][n], 0, 0, 0);
        sacc[1][n] = __builtin_amdgcn_mfma_f32_16x16x32_bf16(qf[1][kk], kf, sacc[1][n], 0, 0, 0);
      }
    }

    if (CAUSAL && c == nch - 1) {
      #pragma unroll
      for (int m = 0; m < 2; m++)
        #pragma unroll
        for (int n = 0; n < 8; n++)
          #pragma unroll
          for (int r = 0; r < 4; r++) {
            int kcol = k0 + n * 16 + lane16;
            int q = q0 + w * 32 + m * 16 + l4 * 4 + r;
            if (kcol > q) sacc[m][n][r] = -1e30f;
          }
    }

    #pragma unroll
    for (int m = 0; m < 2; m++)
      #pragma unroll
      for (int r = 0; r < 4; r++) {
        float smax = sacc[m][0][r];
        #pragma unroll
        for (int n = 1; n < 8; n++) smax = fmaxf(smax, sacc[m][n][r]);
        #pragma unroll
        for (int off = 1; off < 16; off <<= 1) smax = fmaxf(smax, __shfl_xor(smax, off, 64));
        float mold = mrow[m][r];
        float mnew = fmaxf(mold, smax);
        float sc = __expf(mold - mnew);
        float psum = 0.f;
        unsigned short pv[8];
        #pragma unroll
        for (int n = 0; n < 8; n++) {
          float p = __expf(sacc[m][n][r] - mnew);
          psum += p;
          pv[n] = f2bf(p);
        }
        #pragma unroll
        for (int off = 1; off < 16; off <<= 1) psum += __shfl_xor(psum, off, 64);
        lrow[m][r] = lrow[m][r] * sc + psum;
        mrow[m][r] = mnew;
        #pragma unroll
        for (int d4 = 0; d4 < 4; d4++) accO[m][d4][r] *= sc;
        int prow = m * 16 + l4 * 4 + r;
        #pragma unroll
        for (int n = 0; n < 8; n++) {
          int col = n * 16 + lane16;
          Ps[w][prow * 128 + (((col >> 3) ^ (prow & 7)) * 8) + (col & 7)] = pv[n];
        }
      }

    #pragma unroll
    for (int kk = 0; kk < 4; kk++) {
      bf16x8 pa[2];
      #pragma unroll
      for (int m = 0; m < 2; m++) {
        int arow = m * 16 + lane16;
        pa[m] = *reinterpret_cast<const bf16x8*>(
            &Ps[w][arow * 128 + (((kk * 4 + l4) ^ (arow & 7)) * 8)]);
      }
      #pragma unroll
      for (int d4 = 0; d4 < 4; d4++) {
        int vrow = d4 * 16 + lane16;
        bf16x8 vf = *reinterpret_cast<const bf16x8*>(
            &Vs[vrow * 128 + (((kk * 4 + l4) ^ (vrow & 7)) * 8)]);
        accO[0][d4] = __builtin_amdgcn_mfma_f32_16x16x32_bf16(pa[0], vf, accO[0][d4], 0, 0, 0);
        accO[1][d4] = __builtin_amdgcn_mfma_f32_16x16x32_bf16(pa[1], vf, accO[1][d4], 0, 0, 0);
      }
    }
  }

  #pragma unroll
  for (int m = 0; m < 2; m++)
    #pragma unroll
    for (int r = 0; r < 4; r++) {
      float inv = 1.f / lrow[m][r];
      int q = q0 + w * 32 + m * 16 + l4 * 4 + r;
      #pragma unroll
      for (int d4 = 0; d4 < 4; d4++)
        Ob[(long)q * Dc + d4 * 16 + lane16] = f2bf(accO[m][d4][r] * inv);
    }
}

// ---------------------------------------------------------------------------
// MFMA GEMM, 2-phase double-buffered (BK=64).
// C[M,N] = alpha * A[M,K] * BT[N,K]^T (+bias)(+relu)(+res)
// Prefetch tile t+1 (global_load_lds, inverse-swizzled source) before the
// ds_read+MFMA of tile t; single __syncthreads per step (vmcnt drain = fence).
// LDS rows 64 shorts = 128B; XOR key row&7 -> swizzled ds_read_b128, 2-way.
// ---------------------------------------------------------------------------
template <int BM, int BN, int MF, int NF, bool HASBIAS, bool RELU, bool HASRES, bool OUTBF>
__global__ __launch_bounds__(256) void gemm_k(
    const unsigned short* __restrict__ A, long sAb, long sAh, int lda,
    const unsigned short* __restrict__ BT, long sBb, long sBh, int ldb,
    void* Cp, long sCb, long sCh, int ldc,
    const float* __restrict__ bias,
    const float* __restrict__ Res, int ldr,
    int K, int nH, float alpha) {
  constexpr int BK = 64;
  __shared__ __align__(16) unsigned short As[2][BM * BK];
  __shared__ __align__(16) unsigned short Bs[2][BN * BK];

  const int tid = threadIdx.x;
  const int lane = tid & 63;
  const int w = tid >> 6;
  const int wr = w >> 1, wc = w & 1;
  const int lane16 = lane & 15;
  const int l4 = lane >> 4;

  const int z = blockIdx.z;
  const int bb = z / nH, hh = z % nH;
  const long offA = sAb * bb + sAh * hh;
  const long offB = sBb * bb + sBh * hh;
  const long offC = sCb * bb + sCh * hh;

  const int m0 = blockIdx.x * BM;
  const int n0 = blockIdx.y * BN;

  // staging geometry: per wave-instruction, 8 rows x 8 slots; lane = r*8+s
  const int sr = lane >> 3;                 // row within group of 8
  const int sgl = ((lane & 7) ^ sr) * 8;    // inverse-swizzled global slot (shorts)

  const unsigned short* Ab = A + offA + (long)m0 * lda;
  const unsigned short* Bb = BT + offB + (long)n0 * ldb;

  const unsigned short* aP[BM / 32];
  #pragma unroll
  for (int j = 0; j < BM / 32; j++)
    aP[j] = Ab + (long)(w * (BM / 4) + j * 8 + sr) * lda + sgl;
  const unsigned short* bP[BN / 32];
  #pragma unroll
  for (int j = 0; j < BN / 32; j++)
    bP[j] = Bb + (long)(w * (BN / 4) + j * 8 + sr) * ldb + sgl;

  f32x4 acc[MF][NF];
  #pragma unroll
  for (int m = 0; m < MF; m++)
    #pragma unroll
    for (int n = 0; n < NF; n++)
      #pragma unroll
      for (int r = 0; r < 4; r++) acc[m][n][r] = 0.f;

  auto STAGE = [&](int buf, int k0) {
    #pragma unroll
    for (int j = 0; j < BM / 32; j++)
      gl_lds16(aP[j] + k0, &As[buf][(w * (BM / 4) + j * 8) * BK]);
    #pragma unroll
    for (int j = 0; j < BN / 32; j++)
      gl_lds16(bP[j] + k0, &Bs[buf][(w * (BN / 4) + j * 8) * BK]);
  };
  auto COMPUTE = [&](int buf) {
    #pragma unroll
    for (int kk = 0; kk < 2; kk++) {
      bf16x8 af[MF], bfr[NF];
      #pragma unroll
      for (int m = 0; m < MF; m++) {
        int row = wr * MF * 16 + m * 16 + lane16;
        af[m] = *reinterpret_cast<const bf16x8*>(
            &As[buf][row * BK + (((kk * 4 + l4) ^ (lane16 & 7)) * 8)]);
      }
      #pragma unroll
      for (int n = 0; n < NF; n++) {
        int row = wc * NF * 16 + n * 16 + lane16;
        bfr[n] = *reinterpret_cast<const bf16x8*>(
            &Bs[buf][row * BK + (((kk * 4 + l4) ^ (lane16 & 7)) * 8)]);
      }
      #pragma unroll
      for (int m = 0; m < MF; m++)
        #pragma unroll
        for (int n = 0; n < NF; n++)
          acc[m][n] = __builtin_amdgcn_mfma_f32_16x16x32_bf16(af[m], bfr[n], acc[m][n], 0, 0, 0);
    }
  };

  const int nt = K / BK;
  int cur = 0;
  STAGE(0, 0);
  __syncthreads();
  for (int t = 0; t < nt; t++) {
    if (t + 1 < nt) STAGE(cur ^ 1, (t + 1) * BK);
    COMPUTE(cur);
    __syncthreads();   // drains prefetch vmcnt + fences LDS reuse
    cur ^= 1;
  }

  const int r0 = m0 + wr * MF * 16;
  const int c0 = n0 + wc * NF * 16;
  #pragma unroll
  for (int m = 0; m < MF; m++) {
    #pragma unroll
    for (int n = 0; n < NF; n++) {
      #pragma unroll
      for (int r = 0; r < 4; r++) {
        int rr = r0 + m * 16 + l4 * 4 + r;
        int cc = c0 + n * 16 + lane16;
        float v = acc[m][n][r] * alpha;
        if constexpr (HASBIAS) v += bias[cc];
        if constexpr (RELU) v = fmaxf(v, 0.f);
        if constexpr (HASRES) v += Res[offC + (long)rr * ldr + cc];
        if constexpr (OUTBF) ((unsigned short*)Cp)[offC + (long)rr * ldc + cc] = f2bf(v);
        else                 ((float*)Cp)[offC + (long)rr * ldc + cc] = v;
      }
    }
  }
}

// ---------------------------------------------------------------------------
extern "C" void kernel_launch(void* const* d_in, const int* in_sizes, int n_in,
                              void* d_out, int out_size, void* d_ws, size_t ws_size,
                              hipStream_t stream) {
  (void)in_sizes; (void)n_in; (void)out_size;

  const int*   idx      = (const int*)d_in[0];
  const int*   enc_in   = (const int*)d_in[1];
  const float* enc_tok  = (const float*)d_in[2];
  const float* enc_pos  = (const float*)d_in[3];
  const float* enc_qkv  = (const float*)d_in[4];
  const float* enc_wo   = (const float*)d_in[5];
  const float* enc_bo   = (const float*)d_in[6];
  const float* enc_w1   = (const float*)d_in[7];
  const float* enc_b1   = (const float*)d_in[8];
  const float* enc_w2   = (const float*)d_in[9];
  const float* enc_b2   = (const float*)d_in[10];
  const float* enc_ln1g = (const float*)d_in[11];
  const float* enc_ln1b = (const float*)d_in[12];
  const float* enc_ln2g = (const float*)d_in[13];
  const float* enc_ln2b = (const float*)d_in[14];
  const float* enc_lnfg = (const float*)d_in[15];
  const float* enc_lnfb = (const float*)d_in[16];
  const float* dec_tok  = (const float*)d_in[17];
  const float* dec_pos  = (const float*)d_in[18];
  const float* dec_qkv  = (const float*)d_in[19];
  const float* dec_wo   = (const float*)d_in[20];
  const float* dec_bo   = (const float*)d_in[21];
  const float* dec_cqkv = (const float*)d_in[22];
  const float* dec_cwo  = (const float*)d_in[23];
  const float* dec_cbo  = (const float*)d_in[24];
  const float* dec_w1   = (const float*)d_in[25];
  const float* dec_b1   = (const float*)d_in[26];
  const float* dec_w2   = (const float*)d_in[27];
  const float* dec_b2   = (const float*)d_in[28];
  const float* dec_ln1g = (const float*)d_in[29];
  const float* dec_ln1b = (const float*)d_in[30];
  const float* dec_ln2g = (const float*)d_in[31];
  const float* dec_ln2b = (const float*)d_in[32];
  const float* dec_ln3g = (const float*)d_in[33];
  const float* dec_ln3b = (const float*)d_in[34];
  const float* dec_lnfg = (const float*)d_in[35];
  const float* dec_lnfb = (const float*)d_in[36];
  const float* lm_w     = (const float*)d_in[37];
  const float* lm_b     = (const float*)d_in[38];

  constexpr long De2 = (long)Dc * Dc;
  constexpr long DF  = (long)Dc * FFc;

  // ---- d_out head as weight cache (rewritten every call; LM head writes last) ----
  unsigned short* wcache = (unsigned short*)d_out;
  size_t woff = 0;
  auto take = [&](size_t n) { unsigned short* p = wcache + woff; woff += n; return p; };
  unsigned short* enc_qkvT  = take(18ul * De2);
  unsigned short* enc_woT   = take(6ul * De2);
  unsigned short* enc_w1T   = take(6ul * DF);
  unsigned short* enc_w2T   = take(6ul * DF);
  unsigned short* dec_qkvT  = take(18ul * De2);
  unsigned short* dec_woT   = take(6ul * De2);
  unsigned short* dec_cqkvT = take(18ul * De2);
  unsigned short* dec_cwoT  = take(6ul * De2);
  unsigned short* dec_w1T   = take(6ul * DF);
  unsigned short* dec_w2T   = take(6ul * DF);

  // ---- ws layout ----
  char* ws = (char*)d_ws;
  const size_t need = (size_t)Dc * Vc * 2 + 2ull * Mtot * Dc * 4 + 3ull * Mtot * Dc * 2 +
                      3ull * Mtot * Dc * 2 + (size_t)Mtot * FFc * 2 + (size_t)Mtot * Dc * 2 +
                      (size_t)Bc * Hc * HDc * Tc * 2 + 4096;
  if (ws_size < need) return;
  auto takeW = [&](size_t bytes) { char* p = ws; ws += (bytes + 255) & ~255ull; return p; };
  unsigned short* lm_wT = (unsigned short*)takeW((size_t)Dc * Vc * 2);
  float* xe             = (float*)takeW((size_t)Mtot * Dc * 4);
  float* xd             = (float*)takeW((size_t)Mtot * Dc * 4);
  unsigned short* hbf   = (unsigned short*)takeW((size_t)Mtot * Dc * 2);
  unsigned short* qkvb  = (unsigned short*)takeW(3ull * Mtot * Dc * 2);
  unsigned short* ao    = (unsigned short*)takeW((size_t)Mtot * Dc * 2);
  unsigned short* mid   = (unsigned short*)takeW((size_t)Mtot * FFc * 2);
  unsigned short* eo    = (unsigned short*)takeW((size_t)Mtot * Dc * 2);
  unsigned short* vT    = (unsigned short*)takeW((size_t)Bc * Hc * HDc * Tc * 2);
  unsigned short* qb = qkvb;
  unsigned short* kb = qkvb + (size_t)Mtot * Dc;
  unsigned short* vb = qkvb + 2ull * Mtot * Dc;

  const dim3 TB(256);

  // ---- weight conversion ----
  wconv_k<<<dim3(Dc/32, Dc/32, 18), TB, 0, stream>>>(enc_qkv, enc_qkvT, Dc, Dc);
  wconv_k<<<dim3(Dc/32, Dc/32,  6), TB, 0, stream>>>(enc_wo,  enc_woT,  Dc, Dc);
  wconv_k<<<dim3(Dc/32, FFc/32, 6), TB, 0, stream>>>(enc_w1,  enc_w1T,  Dc, FFc);
  wconv_k<<<dim3(FFc/32, Dc/32, 6), TB, 0, stream>>>(enc_w2,  enc_w2T,  FFc, Dc);
  wconv_k<<<dim3(Dc/32, Dc/32, 18), TB, 0, stream>>>(dec_qkv, dec_qkvT, Dc, Dc);
  wconv_k<<<dim3(Dc/32, Dc/32,  6), TB, 0, stream>>>(dec_wo,  dec_woT,  Dc, Dc);
  wconv_k<<<dim3(Dc/32, Dc/32, 18), TB, 0, stream>>>(dec_cqkv,dec_cqkvT,Dc, Dc);
  wconv_k<<<dim3(Dc/32, Dc/32,  6), TB, 0, stream>>>(dec_cwo, dec_cwoT, Dc, Dc);
  wconv_k<<<dim3(Dc/32, FFc/32, 6), TB, 0, stream>>>(dec_w1,  dec_w1T,  Dc, FFc);
  wconv_k<<<dim3(FFc/32, Dc/32, 6), TB, 0, stream>>>(dec_w2,  dec_w2T,  FFc, Dc);
  wconv_k<<<dim3(Dc/32, Vc/32,  1), TB, 0, stream>>>(lm_w,    lm_wT,    Dc, Vc);

  auto LN = [&](const float* X, const float* g, const float* b, unsigned short* o) {
    ln_k<<<dim3(Mtot), TB, 0, stream>>>(X, g, b, o);
  };
  auto QKV3 = [&](const unsigned short* Abf, const unsigned short* W3T) {
    gemm_k<128,64,4,2,false,false,false,true><<<dim3(Mtot/128, Dc/64, 3), TB, 0, stream>>>(
        Abf, 0, 0, Dc, W3T, De2, 0, Dc,
        qkvb, (long)Mtot*Dc, 0, Dc, nullptr, nullptr, 0, Dc, 1, 1.f);
  };
  auto PROJ1 = [&](const unsigned short* Abf, const unsigned short* WT, unsigned short* Cb) {
    gemm_k<128,64,4,2,false,false,false,true><<<dim3(Mtot/128, Dc/64, 1), TB, 0, stream>>>(
        Abf, 0, 0, Dc, WT, 0, 0, Dc,
        Cb, 0, 0, Dc, nullptr, nullptr, 0, Dc, 1, 1.f);
  };
  auto KV2 = [&](const unsigned short* Abf, const unsigned short* W2T) {
    gemm_k<128,64,4,2,false,false,false,true><<<dim3(Mtot/128, Dc/64, 2), TB, 0, stream>>>(
        Abf, 0, 0, Dc, W2T, De2, 0, Dc,
        kb, (long)Mtot*Dc, 0, Dc, nullptr, nullptr, 0, Dc, 1, 1.f);
  };
  auto VT = [&]() {
    vtrans_k<<<dim3(Tc/64, Bc*Hc), TB, 0, stream>>>(vb, vT);
  };
  auto FLASH = [&](bool causal) {
    if (causal) flash_k<true ><<<dim3(Tc/128, Bc*Hc), TB, 0, stream>>>(qb, kb, vT, ao);
    else        flash_k<false><<<dim3(Tc/128, Bc*Hc), TB, 0, stream>>>(qb, kb, vT, ao);
  };
  auto ORES = [&](const unsigned short* Abf, const unsigned short* WT, const float* bias, float* X) {
    gemm_k<128,64,4,2,true,false,true,false><<<dim3(Mtot/128, Dc/64, 1), TB, 0, stream>>>(
        Abf, 0, 0, Dc, WT, 0, 0, Dc,
        X, 0, 0, Dc, bias, X, Dc, Dc, 1, 1.f);
  };
  auto FFN1 = [&](const unsigned short* Abf, const unsigned short* WT, const float* bias) {
    gemm_k<128,128,4,4,true,true,false,true><<<dim3(Mtot/128, FFc/128, 1), TB, 0, stream>>>(
        Abf, 0, 0, Dc, WT, 0, 0, Dc,
        mid, 0, 0, FFc, bias, nullptr, 0, Dc, 1, 1.f);
  };
  auto FFN2 = [&](const unsigned short* WT, const float* bias, float* X) {
    gemm_k<128,64,4,2,true,false,true,false><<<dim3(Mtot/128, Dc/64, 1), TB, 0, stream>>>(
        mid, 0, 0, FFc, WT, 0, 0, FFc,
        X, 0, 0, Dc, bias, X, Dc, FFc, 1, 1.f);
  };

  // ======================= encoder =======================
  embed_k<<<dim3(Mtot), TB, 0, stream>>>(enc_in, enc_tok, enc_pos, xe);
  for (int i = 0; i < Lc; i++) {
    LN(xe, enc_ln1g + i * Dc, enc_ln1b + i * Dc, hbf);
    QKV3(hbf, enc_qkvT + (size_t)i * 3 * De2);
    VT(); FLASH(true);
    ORES(ao, enc_woT + (size_t)i * De2, enc_bo + i * Dc, xe);
    LN(xe, enc_ln2g + i * Dc, enc_ln2b + i * Dc, hbf);
    FFN1(hbf, enc_w1T + (size_t)i * DF, enc_b1 + i * FFc);
    FFN2(enc_w2T + (size_t)i * DF, enc_b2 + i * Dc, xe);
  }
  LN(xe, enc_lnfg, enc_lnfb, eo);

  // ======================= decoder =======================
  embed_k<<<dim3(Mtot), TB, 0, stream>>>(idx, dec_tok, dec_pos, xd);
  for (int i = 0; i < Lc; i++) {
    LN(xd, dec_ln1g + i * Dc, dec_ln1b + i * Dc, hbf);
    QKV3(hbf, dec_qkvT + (size_t)i * 3 * De2);
    VT(); FLASH(true);
    ORES(ao, dec_woT + (size_t)i * De2, dec_bo + i * Dc, xd);
    LN(xd, dec_ln2g + i * Dc, dec_ln2b + i * Dc, hbf);
    PROJ1(hbf, dec_cqkvT + (size_t)i * 3 * De2, qb);
    KV2(eo, dec_cqkvT + (size_t)i * 3 * De2 + De2);
    VT(); FLASH(false);
    ORES(ao, dec_cwoT + (size_t)i * De2, dec_cbo + i * Dc, xd);
    LN(xd, dec_ln3g + i * Dc, dec_ln3b + i * Dc, hbf);
    FFN1(hbf, dec_w1T + (size_t)i * DF, dec_b1 + i * FFc);
    FFN2(dec_w2T + (size_t)i * DF, dec_b2 + i * Dc, xd);
  }
  LN(xd, dec_lnfg, dec_lnfb, hbf);

  // ======================= LM head =======================
  gemm_k<128,128,4,4,true,false,false,false><<<dim3(Mtot/128, Vc/128, 1), TB, 0, stream>>>(
      hbf, 0, 0, Dc, lm_wT, 0, 0, Dc,
      d_out, 0, 0, Vc, lm_b, nullptr, 0, Dc, 1, 1.f);
}